// Round 3
// baseline (4189.328 us; speedup 1.0000x reference)
//
#include <hip/hip_runtime.h>
#include <stdint.h>

#define NPT 32768

typedef unsigned int u32;
typedef unsigned short u16;

typedef short v8s __attribute__((ext_vector_type(8)));
typedef float v4f __attribute__((ext_vector_type(4)));

__device__ __forceinline__ float b2f(u16 u) {
  union { u32 u; float f; } x; x.u = ((u32)u) << 16; return x.f;
}
__device__ __forceinline__ u16 f2b(float f) {
  union { float f; u32 u; } x; x.f = f;
  u32 u = x.u;
  return (u16)((u + 0x7fffu + ((u >> 16) & 1u)) >> 16);
}
// dtype probe: coords[0][0] == 0.0 by construction. fp32 -> u16[1] (high half of 0.0f) == 0.
// bf16 -> u16[1] = bf16(x0) != 0 (x0 = uniform*100).
__device__ __forceinline__ bool probe_f32(const void* coords) {
  return ((const u16*)coords)[1] == 0;
}
__device__ __forceinline__ float ldany(const void* p, long i, bool f32) {
  return f32 ? ((const float*)p)[i] : b2f(((const u16*)p)[i]);
}
__device__ __forceinline__ float wsum(float v) {
#pragma unroll
  for (int m = 1; m < 64; m <<= 1) v += __shfl_xor(v, m, 64);
  return v;
}

// stable insert into ascending sorted 16-list; strict < keeps earlier (lower-index) on ties
__device__ __forceinline__ void insert16(float d, int ci, float (&dist)[16], int (&best)[16]) {
#pragma unroll
  for (int j = 15; j >= 1; --j) {
    bool cjm1 = d < dist[j - 1];
    bool cj = d < dist[j];
    float nd = cjm1 ? dist[j - 1] : (cj ? d : dist[j]);
    int ni = cjm1 ? best[j - 1] : (cj ? ci : best[j]);
    dist[j] = nd; best[j] = ni;
  }
  if (d < dist[0]) { dist[0] = d; best[0] = ci; }
}

// ---------------- input canonicalization ----------------
__global__ __launch_bounds__(256) void conv_coords(const void* __restrict__ coords,
                                                   float* __restrict__ cx, float* __restrict__ cy,
                                                   float* __restrict__ cz) {
  const bool f32 = probe_f32(coords);
  int i = blockIdx.x * 256 + threadIdx.x;
  cx[i] = ldany(coords, (long)i * 4 + 1, f32);
  cy[i] = ldany(coords, (long)i * 4 + 2, f32);
  cz[i] = ldany(coords, (long)i * 4 + 3, f32);
}

__global__ __launch_bounds__(256) void conv_feats(const void* __restrict__ coords,
                                                  const void* __restrict__ feats, u16* __restrict__ featsB) {
  const bool f32 = probe_f32(coords);
  long i = (long)blockIdx.x * 256 + threadIdx.x;
  featsB[i] = f32 ? f2b(((const float*)feats)[i]) : ((const u16*)feats)[i];
}

// ---------------- KNN: brute force, 2 candidate slices ----------------
__global__ __launch_bounds__(256) void knn_slice(const float* __restrict__ cx, const float* __restrict__ cy,
                                                 const float* __restrict__ cz,
                                                 float* __restrict__ du, int* __restrict__ iu) {
  __shared__ float sx[512], sy[512], sz[512];
  const int t = threadIdx.x;
  const int q = blockIdx.x * 256 + t;
  const int slice = blockIdx.y;
  const int base = slice * (NPT / 2);
  const float qx = cx[q], qy = cy[q], qz = cz[q];
  float dist[16]; int best[16];
#pragma unroll
  for (int j = 0; j < 16; j++) { dist[j] = 3.4e38f; best[j] = 0; }

  for (int tile = 0; tile < NPT / 2; tile += 512) {
    __syncthreads();
#pragma unroll
    for (int s = t; s < 512; s += 256) {
      int c = base + tile + s;
      sx[s] = cx[c]; sy[s] = cy[c]; sz[s] = cz[c];
    }
    __syncthreads();
    for (int g = 0; g < 512; ++g) {
      float dx = __fsub_rn(qx, sx[g]), dy = __fsub_rn(qy, sy[g]), dz = __fsub_rn(qz, sz[g]);
      float d = __fadd_rn(__fadd_rn(__fmul_rn(dx, dx), __fmul_rn(dy, dy)), __fmul_rn(dz, dz));
      if (d < dist[15]) insert16(d, base + tile + g, dist, best);
    }
  }
#pragma unroll
  for (int j = 0; j < 16; j++) {
    du[(size_t)(q * 2 + slice) * 16 + j] = dist[j];
    iu[(size_t)(q * 2 + slice) * 16 + j] = best[j];
  }
}

__global__ __launch_bounds__(256) void knn_merge(const float* __restrict__ du, const int* __restrict__ iu,
                                                 int* __restrict__ idxout) {
  const int q = blockIdx.x * 256 + threadIdx.x;
  float dist[16]; int best[16];
#pragma unroll
  for (int j = 0; j < 16; j++) { dist[j] = 3.4e38f; best[j] = 0; }
  for (int s = 0; s < 2; s++) {
#pragma unroll
    for (int j = 0; j < 16; j++) {
      float d = du[(size_t)(q * 2 + s) * 16 + j];
      int i = iu[(size_t)(q * 2 + s) * 16 + j];
      if (d < dist[15]) insert16(d, i, dist, best);
    }
  }
#pragma unroll
  for (int j = 0; j < 16; j++) idxout[(size_t)q * 16 + j] = best[j];
}

// ---------------- small precomputes ----------------
// tbl per layer (1024 floats): [0:384] Wk3(i*128+c), [384:768] Wv3, [768:896] bk_full, [896:1024] bv_full
__global__ __launch_bounds__(128) void prep_tables(
    const void* coords,
    const void* pw0, const void* pb0, const void* kw0, const void* kb0, const void* vw0, const void* vb0,
    const void* pw1, const void* pb1, const void* kw1, const void* kb1, const void* vw1, const void* vb1,
    float* __restrict__ tbl) {
  const bool f32 = probe_f32(coords);
  const int c = threadIdx.x;
  const void* PW[2] = { pw0, pw1 }; const void* PB[2] = { pb0, pb1 };
  const void* KW[2] = { kw0, kw1 }; const void* KB[2] = { kb0, kb1 };
  const void* VW[2] = { vw0, vw1 }; const void* VB[2] = { vb0, vb1 };
#pragma unroll
  for (int l = 0; l < 2; l++) {
    for (int i = 0; i < 3; i++) {
      float ak = 0.f, av = 0.f;
      for (int d = 0; d < 128; d++) {
        float pw = ldany(PW[l], i * 128 + d, f32);
        ak += pw * ldany(KW[l], d * 128 + c, f32);
        av += pw * ldany(VW[l], d * 128 + c, f32);
      }
      tbl[l * 1024 + i * 128 + c] = ak;
      tbl[l * 1024 + 384 + i * 128 + c] = av;
    }
    float bk = 0.f, bv = 0.f;
    for (int d = 0; d < 128; d++) {
      float pb = ldany(PB[l], d, f32);
      bk += pb * ldany(KW[l], d * 128 + c, f32);
      bv += pb * ldany(VW[l], d * 128 + c, f32);
    }
    tbl[l * 1024 + 768 + c] = bk + ldany(KB[l], c, f32);
    tbl[l * 1024 + 896 + c] = bv + ldany(VB[l], c, f32);
  }
}

// repack weights into MFMA B-fragment order: Bf[((tile*4+kq)*64+lane)*8+j] = W[k][col]
__global__ __launch_bounds__(256) void prep_bfrag(const void* __restrict__ coords,
                                                  const void* __restrict__ w0, const void* __restrict__ w1,
                                                  const void* __restrict__ w2, u16* __restrict__ Bf, int nElem) {
  const bool f32 = probe_f32(coords);
  int tid = blockIdx.x * 256 + threadIdx.x;
  if (tid >= nElem) return;
  int j = tid & 7, lane = (tid >> 3) & 63, kq = (tid >> 9) & 3, tile = tid >> 11;
  int k = kq * 32 + ((lane >> 4) << 3) + j;
  int col = tile * 16 + (lane & 15);
  const void* w = (col < 128) ? w0 : ((col < 256) ? w1 : w2);
  long off = (long)k * 128 + (col & 127);
  Bf[tid] = f32 ? f2b(((const float*)w)[off]) : ((const u16*)w)[off];
}

// ---------------- GEMM: A[M,128] bf16 x Bf ----------------
// mode 0: cols 0..127 -> Qb (bf16, +bias); cols 128..383 -> KVb (bf16, no bias)
// mode 1: cols 0..127 -> outF (fp32, +bias)
__global__ __launch_bounds__(256) void gemm_kernel(const void* __restrict__ coords,
                                                   const u16* __restrict__ A, const u16* __restrict__ Bf,
                                                   const void* __restrict__ bias, u16* __restrict__ Qb,
                                                   u16* __restrict__ KVb, float* __restrict__ outF,
                                                   int mode, int ntiles) {
  const bool f32 = probe_f32(coords);
  const int lane = threadIdx.x & 63;
  const int wave = threadIdx.x >> 6;
  const int r0 = blockIdx.x * 64 + wave * 16;
  const int quad = lane >> 4, lr = lane & 15;
  v8s a[4];
#pragma unroll
  for (int kq = 0; kq < 4; kq++) {
    union { uint4 u; v8s s; } c;
    c.u = *(const uint4*)(A + (size_t)(r0 + lr) * 128 + kq * 32 + quad * 8);
    a[kq] = c.s;
  }
  for (int tile = 0; tile < ntiles; ++tile) {
    v4f acc = { 0.f, 0.f, 0.f, 0.f };
#pragma unroll
    for (int kq = 0; kq < 4; kq++) {
      union { uint4 u; v8s s; } c;
      c.u = *(const uint4*)(Bf + ((size_t)(tile * 4 + kq) * 64 + lane) * 8);
      acc = __builtin_amdgcn_mfma_f32_16x16x32_bf16(a[kq], c.s, acc, 0, 0, 0);
    }
    int col = tile * 16 + lr;
    if (mode == 0) {
      if (col < 128) {
        float bb = ldany(bias, col, f32);
#pragma unroll
        for (int r = 0; r < 4; r++) Qb[(size_t)(r0 + quad * 4 + r) * 128 + col] = f2b(acc[r] + bb);
      } else {
#pragma unroll
        for (int r = 0; r < 4; r++) KVb[(size_t)(r0 + quad * 4 + r) * 256 + (col - 128)] = f2b(acc[r]);
      }
    } else {
      float bb = ldany(bias, col, f32);
#pragma unroll
      for (int r = 0; r < 4; r++) outF[(size_t)(r0 + quad * 4 + r) * 128 + col] = acc[r] + bb;
    }
  }
}

// ---------------- fused neighborhood attention (one wave per point) ----------------
// mode 0: out = bf16(o)               (layer-0 output, feeds layer-1 GEMM)
// mode 1: out = bf16(LN(feats+o))     (fused residual+LN with g,be; eps=128)
__global__ __launch_bounds__(256) void attn_kernel(const void* __restrict__ coordsRaw,
                                                   const float* __restrict__ cx, const float* __restrict__ cy,
                                                   const float* __restrict__ cz, const int* __restrict__ idx,
                                                   const u16* __restrict__ Qb, const u16* __restrict__ KVb,
                                                   const float* __restrict__ tbl, const void* __restrict__ feats,
                                                   const void* __restrict__ g, const void* __restrict__ be,
                                                   u16* __restrict__ outB, int mode) {
  const int lane = threadIdx.x & 63;
  const int n = blockIdx.x * 4 + (threadIdx.x >> 6);
  const int c0 = 2 * lane;
  u32 qu = *(const u32*)(Qb + (size_t)n * 128 + c0);
  const float q0 = b2f((u16)(qu & 0xffffu)), q1 = b2f((u16)(qu >> 16));
  float p0 = tbl[c0] * q0 + tbl[c0 + 1] * q1;
  float p1 = tbl[128 + c0] * q0 + tbl[128 + c0 + 1] * q1;
  float p2 = tbl[256 + c0] * q0 + tbl[256 + c0 + 1] * q1;
  float p3 = tbl[768 + c0] * q0 + tbl[768 + c0 + 1] * q1;
  p0 = wsum(p0); p1 = wsum(p1); p2 = wsum(p2); p3 = wsum(p3);
  const float qx = cx[n], qy = cy[n], qz = cz[n];
  int jj[16]; float sc[16], nx[16], ny[16], nz[16];
#pragma unroll
  for (int k = 0; k < 16; k++) {
    int j = idx[(size_t)n * 16 + k];
    jj[k] = j;
    nx[k] = qx - cx[j];
    ny[k] = qy - cy[j];
    nz[k] = qz - cz[j];
    u32 u = *(const u32*)(KVb + (size_t)j * 256 + c0);
    float s = wsum(b2f((u16)(u & 0xffffu)) * q0 + b2f((u16)(u >> 16)) * q1);
    sc[k] = (s + nx[k] * p0 + ny[k] * p1 + nz[k] * p2 + p3) * 0.08838834764831845f; // 1/sqrt(128)
  }
  float m = sc[0];
#pragma unroll
  for (int k = 1; k < 16; k++) m = fmaxf(m, sc[k]);
  float ssum = 0.f;
#pragma unroll
  for (int k = 0; k < 16; k++) { sc[k] = expf(sc[k] - m); ssum += sc[k]; }
  const float inv = 1.0f / ssum;
  float sA = 0.f, wx = 0.f, wy = 0.f, wz = 0.f, a0 = 0.f, a1 = 0.f;
#pragma unroll
  for (int k = 0; k < 16; k++) {
    float a = sc[k] * inv;
    sA += a; wx += a * nx[k]; wy += a * ny[k]; wz += a * nz[k];
    u32 u = *(const u32*)(KVb + (size_t)jj[k] * 256 + 128 + c0);
    a0 += a * b2f((u16)(u & 0xffffu));
    a1 += a * b2f((u16)(u >> 16));
  }
  float o0 = a0 + wx * tbl[384 + c0] + wy * tbl[512 + c0] + wz * tbl[640 + c0] + sA * tbl[896 + c0];
  float o1 = a1 + wx * tbl[384 + c0 + 1] + wy * tbl[512 + c0 + 1] + wz * tbl[640 + c0 + 1] + sA * tbl[896 + c0 + 1];
  if (mode == 1) {
    const bool f32 = probe_f32(coordsRaw);
    float x0 = ldany(feats, (long)n * 128 + c0, f32) + o0;
    float x1 = ldany(feats, (long)n * 128 + c0 + 1, f32) + o1;
    float mu = wsum(x0 + x1) * (1.f / 128.f);
    float d0 = x0 - mu, d1 = x1 - mu;
    float var = wsum(d0 * d0 + d1 * d1) * (1.f / 128.f);
    float rinv = 1.0f / sqrtf(var + 128.0f);
    o0 = d0 * rinv * ldany(g, c0, f32) + ldany(be, c0, f32);
    o1 = d1 * rinv * ldany(g, c0 + 1, f32) + ldany(be, c0 + 1, f32);
  }
  ((u32*)outB)[(size_t)n * 64 + lane] = (u32)f2b(o0) | ((u32)f2b(o1) << 16);
}

// ---------------- final LN: x = bf16(hB) + h1F; out = LN(x)*g+be (eps=128), dual-format store ----------------
__global__ __launch_bounds__(256) void ln_final(const void* __restrict__ coords,
                                                const u16* __restrict__ hB, const float* __restrict__ h1F,
                                                const void* __restrict__ g, const void* __restrict__ be,
                                                void* __restrict__ outAny) {
  const bool f32 = probe_f32(coords);
  const int lane = threadIdx.x & 63;
  const int n = blockIdx.x * 4 + (threadIdx.x >> 6);
  const int c0 = 2 * lane;
  u32 u = *(const u32*)(hB + (size_t)n * 128 + c0);
  float2 h1 = *(const float2*)(h1F + (size_t)n * 128 + c0);
  float x0 = b2f((u16)(u & 0xffffu)) + h1.x;
  float x1 = b2f((u16)(u >> 16)) + h1.y;
  float mu = wsum(x0 + x1) * (1.f / 128.f);
  float d0 = x0 - mu, d1 = x1 - mu;
  float var = wsum(d0 * d0 + d1 * d1) * (1.f / 128.f);
  float rinv = 1.0f / sqrtf(var + 128.0f);
  float y0 = d0 * rinv * ldany(g, c0, f32) + ldany(be, c0, f32);
  float y1 = d1 * rinv * ldany(g, c0 + 1, f32) + ldany(be, c0 + 1, f32);
  if (f32) {
    *(float2*)((float*)outAny + (size_t)n * 128 + c0) = make_float2(y0, y1);
  } else {
    ((u32*)outAny)[(size_t)n * 64 + lane] = (u32)f2b(y0) | ((u32)f2b(y1) << 16);
  }
}

extern "C" void kernel_launch(void* const* d_in, const int* in_sizes, int n_in,
                              void* d_out, int out_size, void* d_ws, size_t ws_size,
                              hipStream_t stream) {
  (void)in_sizes; (void)n_in; (void)out_size; (void)ws_size;
  const void* coords = d_in[0];
  const void* feats = d_in[1];
  const void* pos_w = d_in[2];
  const void* pos_b = d_in[3];
  const void* pos1_w = d_in[4];
  const void* pos1_b = d_in[5];
  const void* qw0 = d_in[6];
  const void* qb0 = d_in[7];
  const void* kw0 = d_in[8];
  const void* kb0 = d_in[9];
  const void* vw0 = d_in[10];
  const void* vb0 = d_in[11];
  const void* qw1 = d_in[12];
  const void* qb1 = d_in[13];
  const void* kw1 = d_in[14];
  const void* kb1 = d_in[15];
  const void* vw1 = d_in[16];
  const void* vb1 = d_in[17];
  const void* lin_w = d_in[18];
  const void* lin_b = d_in[19];
  const void* g0 = d_in[20];
  const void* be0 = d_in[21];
  const void* g1 = d_in[22];
  const void* be1 = d_in[23];

  // Workspace layout (~42.6 MiB total), all offsets 16B-aligned:
  char* w = (char*)d_ws;
  int* idxp = (int*)(w + 0);                  // [0, 2,097,152)
  float* cx = (float*)(w + 2097152);          // 128 KiB
  float* cy = (float*)(w + 2228224);
  float* cz = (float*)(w + 2359296);
  float* tbl = (float*)(w + 2490368);         // 8 KiB
  u16* Bf0 = (u16*)(w + 2498560);             // 96 KiB
  u16* Bf1 = (u16*)(w + 2596864);             // 96 KiB
  u16* BfL = (u16*)(w + 2695168);             // 32 KiB
  u16* featsB = (u16*)(w + 2727936);          // 8 MiB  -> ends 11,116,544
  u16* oB = (u16*)(w + 11116544);             // 8 MiB  (o, then h)  -> ends 19,505,152
  u16* Qb = (u16*)(w + 19505152);             // 8 MiB  -> ends 27,893,760
  u16* KVb = (u16*)(w + 27893760);            // 16 MiB -> ends 44,670,976
  float* du = (float*)(w + 19505152);         // 4 MiB  (aliases Qb; dead before gemm L0)
  int* iu = (int*)(w + 23699456);             // 4 MiB  (aliases Qb)
  float* h1F = (float*)(w + 19505152);        // 16 MiB (aliases Qb+KVb; they are dead by then)

  hipLaunchKernelGGL(conv_coords, dim3(128), dim3(256), 0, stream, coords, cx, cy, cz);
  hipLaunchKernelGGL(conv_feats, dim3(16384), dim3(256), 0, stream, coords, feats, featsB);
  hipLaunchKernelGGL(prep_tables, dim3(1), dim3(128), 0, stream, coords,
                     pos_w, pos_b, kw0, kb0, vw0, vb0, pos1_w, pos1_b, kw1, kb1, vw1, vb1, tbl);
  hipLaunchKernelGGL(prep_bfrag, dim3(192), dim3(256), 0, stream, coords, qw0, kw0, vw0, Bf0, 49152);
  hipLaunchKernelGGL(prep_bfrag, dim3(192), dim3(256), 0, stream, coords, qw1, kw1, vw1, Bf1, 49152);
  hipLaunchKernelGGL(prep_bfrag, dim3(64), dim3(256), 0, stream, coords, lin_w, lin_w, lin_w, BfL, 16384);

  hipLaunchKernelGGL(knn_slice, dim3(128, 2), dim3(256), 0, stream, cx, cy, cz, du, iu);
  hipLaunchKernelGGL(knn_merge, dim3(128), dim3(256), 0, stream, du, iu, idxp);

  // layer 0: Q/K/V tables from featsB, attention -> o (bf16) into oB
  hipLaunchKernelGGL(gemm_kernel, dim3(512), dim3(256), 0, stream, coords, featsB, Bf0, qb0, Qb, KVb,
                     (float*)nullptr, 0, 24);
  hipLaunchKernelGGL(attn_kernel, dim3(8192), dim3(256), 0, stream, coords, cx, cy, cz, idxp, Qb, KVb, tbl,
                     (const void*)nullptr, (const void*)nullptr, (const void*)nullptr, oB, 0);
  // layer 1: Q/K/V from o, attention fused with LN0 -> h (bf16) into oB
  hipLaunchKernelGGL(gemm_kernel, dim3(512), dim3(256), 0, stream, coords, oB, Bf1, qb1, Qb, KVb,
                     (float*)nullptr, 0, 24);
  hipLaunchKernelGGL(attn_kernel, dim3(8192), dim3(256), 0, stream, coords, cx, cy, cz, idxp, Qb, KVb, tbl + 1024,
                     feats, g0, be0, oB, 1);
  // h1 = h @ lin_w + lin_b (fp32), out = LN(h + h1) in the input dtype
  hipLaunchKernelGGL(gemm_kernel, dim3(512), dim3(256), 0, stream, coords, oB, BfL, lin_b,
                     (u16*)nullptr, (u16*)nullptr, h1F, 1, 8);
  hipLaunchKernelGGL(ln_final, dim3(8192), dim3(256), 0, stream, coords, oB, h1F, g1, be1, d_out);
}

// Round 4
// 962.410 us; speedup vs baseline: 4.3530x; 4.3530x over previous
//
#include <hip/hip_runtime.h>
#include <stdint.h>

#define NPT 32768

typedef unsigned int u32;
typedef unsigned short u16;

typedef short v8s __attribute__((ext_vector_type(8)));
typedef float v4f __attribute__((ext_vector_type(4)));

__device__ __forceinline__ float b2f(u16 u) {
  union { u32 u; float f; } x; x.u = ((u32)u) << 16; return x.f;
}
__device__ __forceinline__ u16 f2b(float f) {
  union { float f; u32 u; } x; x.f = f;
  u32 u = x.u;
  return (u16)((u + 0x7fffu + ((u >> 16) & 1u)) >> 16);
}
// dtype probe: coords[0][0] == 0.0 by construction. fp32 -> u16[1] (high half of 0.0f) == 0.
// bf16 -> u16[1] = bf16(x0) != 0 (x0 = uniform*100).
__device__ __forceinline__ bool probe_f32(const void* coords) {
  return ((const u16*)coords)[1] == 0;
}
__device__ __forceinline__ float ldany(const void* p, long i, bool f32) {
  return f32 ? ((const float*)p)[i] : b2f(((const u16*)p)[i]);
}
__device__ __forceinline__ float wsum(float v) {
#pragma unroll
  for (int m = 1; m < 64; m <<= 1) v += __shfl_xor(v, m, 64);
  return v;
}

// lexicographic (d, idx) insert into sorted min-16 list: identical set semantics to
// index-order strict-< insertion (ties -> lower index wins), i.e. top_k behavior.
__device__ __forceinline__ void insert16t(float d, int ci, float (&dist)[16], int (&best)[16]) {
#pragma unroll
  for (int j = 15; j >= 1; --j) {
    bool cjm1 = (d < dist[j - 1]) || (d == dist[j - 1] && ci < best[j - 1]);
    bool cj = (d < dist[j]) || (d == dist[j] && ci < best[j]);
    float nd = cjm1 ? dist[j - 1] : (cj ? d : dist[j]);
    int ni = cjm1 ? best[j - 1] : (cj ? ci : best[j]);
    dist[j] = nd; best[j] = ni;
  }
  if ((d < dist[0]) || (d == dist[0] && ci < best[0])) { dist[0] = d; best[0] = ci; }
}

// ---------------- input canonicalization ----------------
__global__ __launch_bounds__(256) void conv_coords(const void* __restrict__ coords,
                                                   float* __restrict__ cx, float* __restrict__ cy,
                                                   float* __restrict__ cz) {
  const bool f32 = probe_f32(coords);
  int i = blockIdx.x * 256 + threadIdx.x;
  cx[i] = ldany(coords, (long)i * 4 + 1, f32);
  cy[i] = ldany(coords, (long)i * 4 + 2, f32);
  cz[i] = ldany(coords, (long)i * 4 + 3, f32);
}

__global__ __launch_bounds__(256) void conv_feats(const void* __restrict__ coords,
                                                  const void* __restrict__ feats, u16* __restrict__ featsB) {
  const bool f32 = probe_f32(coords);
  long i = (long)blockIdx.x * 256 + threadIdx.x;
  featsB[i] = f32 ? f2b(((const float*)feats)[i]) : ((const u16*)feats)[i];
}

// ---------------- exact KNN via 16^3 spatial grid ----------------
#define GC 16
#define GH 6.25f
#define GINV 0.16f

__device__ __forceinline__ int cell1d(float v) {
  int c = (int)(v * GINV);
  return c > (GC - 1) ? (GC - 1) : (c < 0 ? 0 : c);
}

__global__ __launch_bounds__(256) void grid_zero(int* __restrict__ cellStart) {
  int i = blockIdx.x * 256 + threadIdx.x;
  if (i < GC * GC * GC + 1) cellStart[i] = 0;
}

__global__ __launch_bounds__(256) void grid_hist(const float* __restrict__ cx, const float* __restrict__ cy,
                                                 const float* __restrict__ cz, int* __restrict__ cellStart,
                                                 int* __restrict__ pcell) {
  int i = blockIdx.x * 256 + threadIdx.x;
  int c = (cell1d(cz[i]) * GC + cell1d(cy[i])) * GC + cell1d(cx[i]);
  pcell[i] = c;
  atomicAdd(&cellStart[c + 1], 1);
}

__global__ __launch_bounds__(256) void grid_scan(int* __restrict__ cellStart, int* __restrict__ cellPtr) {
  __shared__ int part[256];
  const int t = threadIdx.x;
  int local[16]; int s = 0;
#pragma unroll
  for (int i = 0; i < 16; i++) { local[i] = cellStart[1 + t * 16 + i]; s += local[i]; }
  part[t] = s;
  __syncthreads();
  for (int off = 1; off < 256; off <<= 1) {
    int v = (t >= off) ? part[t - off] : 0;
    __syncthreads();
    part[t] += v;
    __syncthreads();
  }
  int run = (t == 0) ? 0 : part[t - 1];
#pragma unroll
  for (int i = 0; i < 16; i++) {
    int c = t * 16 + i;
    cellPtr[c] = run;
    run += local[i];
    cellStart[c + 1] = run;
  }
}

__global__ __launch_bounds__(256) void grid_scatter(const float* __restrict__ cx, const float* __restrict__ cy,
                                                    const float* __restrict__ cz, const int* __restrict__ pcell,
                                                    int* __restrict__ cellPtr, float4* __restrict__ sortedP) {
  int i = blockIdx.x * 256 + threadIdx.x;
  int c = pcell[i];
  int pos = atomicAdd(&cellPtr[c], 1);
  sortedP[pos] = make_float4(cx[i], cy[i], cz[i], __int_as_float(i));
}

__global__ __launch_bounds__(256) void knn_grid(const float4* __restrict__ sortedP,
                                                const int* __restrict__ cellStart,
                                                int* __restrict__ idxout) {
  const int t = blockIdx.x * 256 + threadIdx.x;
  const float4 p = sortedP[t];
  const float qx = p.x, qy = p.y, qz = p.z;
  const int qi = __float_as_int(p.w);
  const int qcx = cell1d(qx), qcy = cell1d(qy), qcz = cell1d(qz);
  float dist[16]; int best[16];
#pragma unroll
  for (int j = 0; j < 16; j++) { dist[j] = 3.4e38f; best[j] = 0x7fffffff; }

  auto scan_range = [&](int s0, int s1) {
    for (int u = s0; u < s1; ++u) {
      float4 sp = sortedP[u];
      float dx = __fsub_rn(qx, sp.x), dy = __fsub_rn(qy, sp.y), dzc = __fsub_rn(qz, sp.z);
      float d = __fadd_rn(__fadd_rn(__fmul_rn(dx, dx), __fmul_rn(dy, dy)), __fmul_rn(dzc, dzc));
      int ci = __float_as_int(sp.w);
      if (d < dist[15] || (d == dist[15] && ci < best[15])) insert16t(d, ci, dist, best);
    }
  };

  for (int r = 0; r < GC; ++r) {
    int zlo = qcz - r < 0 ? 0 : qcz - r, zhi = qcz + r > GC - 1 ? GC - 1 : qcz + r;
    for (int cz_ = zlo; cz_ <= zhi; ++cz_) {
      int adz = cz_ - qcz; adz = adz < 0 ? -adz : adz;
      bool ez = (adz == r);
      int ylo = qcy - r < 0 ? 0 : qcy - r, yhi = qcy + r > GC - 1 ? GC - 1 : qcy + r;
      for (int cy_ = ylo; cy_ <= yhi; ++cy_) {
        int ady = cy_ - qcy; ady = ady < 0 ? -ady : ady;
        bool ey = (ady == r);
        int rowbase = (cz_ * GC + cy_) * GC;
        if (ez || ey) {
          int xlo = qcx - r < 0 ? 0 : qcx - r, xhi = qcx + r > GC - 1 ? GC - 1 : qcx + r;
          scan_range(cellStart[rowbase + xlo], cellStart[rowbase + xhi + 1]);
        } else {
          int xm = qcx - r, xp = qcx + r;
          if (xm >= 0) scan_range(cellStart[rowbase + xm], cellStart[rowbase + xm + 1]);
          if (xp <= GC - 1) scan_range(cellStart[rowbase + xp], cellStart[rowbase + xp + 1]);
        }
      }
    }
    float bound = GH * (float)r;
    if (dist[15] < bound * bound * 0.998f) break;  // margin covers fp rounding of d and cell assignment
  }
#pragma unroll
  for (int j = 0; j < 16; j++) idxout[(size_t)qi * 16 + j] = best[j];
}

// ---------------- small precomputes ----------------
// tbl per layer (1024 floats): [0:384] Wk3(i*128+c), [384:768] Wv3, [768:896] bk_full, [896:1024] bv_full
__global__ __launch_bounds__(128) void prep_tables(
    const void* coords,
    const void* pw0, const void* pb0, const void* kw0, const void* kb0, const void* vw0, const void* vb0,
    const void* pw1, const void* pb1, const void* kw1, const void* kb1, const void* vw1, const void* vb1,
    float* __restrict__ tbl) {
  const bool f32 = probe_f32(coords);
  const int c = threadIdx.x;
  const void* PW[2] = { pw0, pw1 }; const void* PB[2] = { pb0, pb1 };
  const void* KW[2] = { kw0, kw1 }; const void* KB[2] = { kb0, kb1 };
  const void* VW[2] = { vw0, vw1 }; const void* VB[2] = { vb0, vb1 };
#pragma unroll
  for (int l = 0; l < 2; l++) {
    for (int i = 0; i < 3; i++) {
      float ak = 0.f, av = 0.f;
      for (int d = 0; d < 128; d++) {
        float pw = ldany(PW[l], i * 128 + d, f32);
        ak += pw * ldany(KW[l], d * 128 + c, f32);
        av += pw * ldany(VW[l], d * 128 + c, f32);
      }
      tbl[l * 1024 + i * 128 + c] = ak;
      tbl[l * 1024 + 384 + i * 128 + c] = av;
    }
    float bk = 0.f, bv = 0.f;
    for (int d = 0; d < 128; d++) {
      float pb = ldany(PB[l], d, f32);
      bk += pb * ldany(KW[l], d * 128 + c, f32);
      bv += pb * ldany(VW[l], d * 128 + c, f32);
    }
    tbl[l * 1024 + 768 + c] = bk + ldany(KB[l], c, f32);
    tbl[l * 1024 + 896 + c] = bv + ldany(VB[l], c, f32);
  }
}

// repack weights into MFMA B-fragment order: Bf[((tile*4+kq)*64+lane)*8+j] = W[k][col]
__global__ __launch_bounds__(256) void prep_bfrag(const void* __restrict__ coords,
                                                  const void* __restrict__ w0, const void* __restrict__ w1,
                                                  const void* __restrict__ w2, u16* __restrict__ Bf, int nElem) {
  const bool f32 = probe_f32(coords);
  int tid = blockIdx.x * 256 + threadIdx.x;
  if (tid >= nElem) return;
  int j = tid & 7, lane = (tid >> 3) & 63, kq = (tid >> 9) & 3, tile = tid >> 11;
  int k = kq * 32 + ((lane >> 4) << 3) + j;
  int col = tile * 16 + (lane & 15);
  const void* w = (col < 128) ? w0 : ((col < 256) ? w1 : w2);
  long off = (long)k * 128 + (col & 127);
  Bf[tid] = f32 ? f2b(((const float*)w)[off]) : ((const u16*)w)[off];
}

// ---------------- GEMM: A[M,128] bf16 x Bf ----------------
// mode 0: cols 0..127 -> Qb (bf16, +bias); cols 128..383 -> KVb (bf16, no bias)
// mode 1: cols 0..127 -> outF (fp32, +bias)
__global__ __launch_bounds__(256) void gemm_kernel(const void* __restrict__ coords,
                                                   const u16* __restrict__ A, const u16* __restrict__ Bf,
                                                   const void* __restrict__ bias, u16* __restrict__ Qb,
                                                   u16* __restrict__ KVb, float* __restrict__ outF,
                                                   int mode, int ntiles) {
  const bool f32 = probe_f32(coords);
  const int lane = threadIdx.x & 63;
  const int wave = threadIdx.x >> 6;
  const int r0 = blockIdx.x * 64 + wave * 16;
  const int quad = lane >> 4, lr = lane & 15;
  v8s a[4];
#pragma unroll
  for (int kq = 0; kq < 4; kq++) {
    union { uint4 u; v8s s; } c;
    c.u = *(const uint4*)(A + (size_t)(r0 + lr) * 128 + kq * 32 + quad * 8);
    a[kq] = c.s;
  }
  for (int tile = 0; tile < ntiles; ++tile) {
    v4f acc = { 0.f, 0.f, 0.f, 0.f };
#pragma unroll
    for (int kq = 0; kq < 4; kq++) {
      union { uint4 u; v8s s; } c;
      c.u = *(const uint4*)(Bf + ((size_t)(tile * 4 + kq) * 64 + lane) * 8);
      acc = __builtin_amdgcn_mfma_f32_16x16x32_bf16(a[kq], c.s, acc, 0, 0, 0);
    }
    int col = tile * 16 + lr;
    if (mode == 0) {
      if (col < 128) {
        float bb = ldany(bias, col, f32);
#pragma unroll
        for (int r = 0; r < 4; r++) Qb[(size_t)(r0 + quad * 4 + r) * 128 + col] = f2b(acc[r] + bb);
      } else {
#pragma unroll
        for (int r = 0; r < 4; r++) KVb[(size_t)(r0 + quad * 4 + r) * 256 + (col - 128)] = f2b(acc[r]);
      }
    } else {
      float bb = ldany(bias, col, f32);
#pragma unroll
      for (int r = 0; r < 4; r++) outF[(size_t)(r0 + quad * 4 + r) * 128 + col] = acc[r] + bb;
    }
  }
}

// ---------------- fused neighborhood attention (one wave per point) ----------------
// mode 0: out = bf16(o)               (layer-0 output, feeds layer-1 GEMM)
// mode 1: out = bf16(LN(feats+o))     (fused residual+LN with g,be; eps=128)
__global__ __launch_bounds__(256) void attn_kernel(const void* __restrict__ coordsRaw,
                                                   const float* __restrict__ cx, const float* __restrict__ cy,
                                                   const float* __restrict__ cz, const int* __restrict__ idx,
                                                   const u16* __restrict__ Qb, const u16* __restrict__ KVb,
                                                   const float* __restrict__ tbl, const void* __restrict__ feats,
                                                   const void* __restrict__ g, const void* __restrict__ be,
                                                   u16* __restrict__ outB, int mode) {
  const int lane = threadIdx.x & 63;
  const int n = blockIdx.x * 4 + (threadIdx.x >> 6);
  const int c0 = 2 * lane;
  u32 qu = *(const u32*)(Qb + (size_t)n * 128 + c0);
  const float q0 = b2f((u16)(qu & 0xffffu)), q1 = b2f((u16)(qu >> 16));
  float p0 = tbl[c0] * q0 + tbl[c0 + 1] * q1;
  float p1 = tbl[128 + c0] * q0 + tbl[128 + c0 + 1] * q1;
  float p2 = tbl[256 + c0] * q0 + tbl[256 + c0 + 1] * q1;
  float p3 = tbl[768 + c0] * q0 + tbl[768 + c0 + 1] * q1;
  p0 = wsum(p0); p1 = wsum(p1); p2 = wsum(p2); p3 = wsum(p3);
  const float qx = cx[n], qy = cy[n], qz = cz[n];
  int jj[16]; float sc[16], nx[16], ny[16], nz[16];
#pragma unroll
  for (int k = 0; k < 16; k++) {
    int j = idx[(size_t)n * 16 + k];
    jj[k] = j;
    nx[k] = qx - cx[j];
    ny[k] = qy - cy[j];
    nz[k] = qz - cz[j];
    u32 u = *(const u32*)(KVb + (size_t)j * 256 + c0);
    float s = wsum(b2f((u16)(u & 0xffffu)) * q0 + b2f((u16)(u >> 16)) * q1);
    sc[k] = (s + nx[k] * p0 + ny[k] * p1 + nz[k] * p2 + p3) * 0.08838834764831845f; // 1/sqrt(128)
  }
  float m = sc[0];
#pragma unroll
  for (int k = 1; k < 16; k++) m = fmaxf(m, sc[k]);
  float ssum = 0.f;
#pragma unroll
  for (int k = 0; k < 16; k++) { sc[k] = expf(sc[k] - m); ssum += sc[k]; }
  const float inv = 1.0f / ssum;
  float sA = 0.f, wx = 0.f, wy = 0.f, wz = 0.f, a0 = 0.f, a1 = 0.f;
#pragma unroll
  for (int k = 0; k < 16; k++) {
    float a = sc[k] * inv;
    sA += a; wx += a * nx[k]; wy += a * ny[k]; wz += a * nz[k];
    u32 u = *(const u32*)(KVb + (size_t)jj[k] * 256 + 128 + c0);
    a0 += a * b2f((u16)(u & 0xffffu));
    a1 += a * b2f((u16)(u >> 16));
  }
  float o0 = a0 + wx * tbl[384 + c0] + wy * tbl[512 + c0] + wz * tbl[640 + c0] + sA * tbl[896 + c0];
  float o1 = a1 + wx * tbl[384 + c0 + 1] + wy * tbl[512 + c0 + 1] + wz * tbl[640 + c0 + 1] + sA * tbl[896 + c0 + 1];
  if (mode == 1) {
    const bool f32 = probe_f32(coordsRaw);
    float x0 = ldany(feats, (long)n * 128 + c0, f32) + o0;
    float x1 = ldany(feats, (long)n * 128 + c0 + 1, f32) + o1;
    float mu = wsum(x0 + x1) * (1.f / 128.f);
    float d0 = x0 - mu, d1 = x1 - mu;
    float var = wsum(d0 * d0 + d1 * d1) * (1.f / 128.f);
    float rinv = 1.0f / sqrtf(var + 128.0f);
    o0 = d0 * rinv * ldany(g, c0, f32) + ldany(be, c0, f32);
    o1 = d1 * rinv * ldany(g, c0 + 1, f32) + ldany(be, c0 + 1, f32);
  }
  ((u32*)outB)[(size_t)n * 64 + lane] = (u32)f2b(o0) | ((u32)f2b(o1) << 16);
}

// ---------------- final LN: x = bf16(hB) + h1F; out = LN(x)*g+be (eps=128), dual-format store ----------------
__global__ __launch_bounds__(256) void ln_final(const void* __restrict__ coords,
                                                const u16* __restrict__ hB, const float* __restrict__ h1F,
                                                const void* __restrict__ g, const void* __restrict__ be,
                                                void* __restrict__ outAny) {
  const bool f32 = probe_f32(coords);
  const int lane = threadIdx.x & 63;
  const int n = blockIdx.x * 4 + (threadIdx.x >> 6);
  const int c0 = 2 * lane;
  u32 u = *(const u32*)(hB + (size_t)n * 128 + c0);
  float2 h1 = *(const float2*)(h1F + (size_t)n * 128 + c0);
  float x0 = b2f((u16)(u & 0xffffu)) + h1.x;
  float x1 = b2f((u16)(u >> 16)) + h1.y;
  float mu = wsum(x0 + x1) * (1.f / 128.f);
  float d0 = x0 - mu, d1 = x1 - mu;
  float var = wsum(d0 * d0 + d1 * d1) * (1.f / 128.f);
  float rinv = 1.0f / sqrtf(var + 128.0f);
  float y0 = d0 * rinv * ldany(g, c0, f32) + ldany(be, c0, f32);
  float y1 = d1 * rinv * ldany(g, c0 + 1, f32) + ldany(be, c0 + 1, f32);
  if (f32) {
    *(float2*)((float*)outAny + (size_t)n * 128 + c0) = make_float2(y0, y1);
  } else {
    ((u32*)outAny)[(size_t)n * 64 + lane] = (u32)f2b(y0) | ((u32)f2b(y1) << 16);
  }
}

extern "C" void kernel_launch(void* const* d_in, const int* in_sizes, int n_in,
                              void* d_out, int out_size, void* d_ws, size_t ws_size,
                              hipStream_t stream) {
  (void)in_sizes; (void)n_in; (void)out_size; (void)ws_size;
  const void* coords = d_in[0];
  const void* feats = d_in[1];
  const void* pos_w = d_in[2];
  const void* pos_b = d_in[3];
  const void* pos1_w = d_in[4];
  const void* pos1_b = d_in[5];
  const void* qw0 = d_in[6];
  const void* qb0 = d_in[7];
  const void* kw0 = d_in[8];
  const void* kb0 = d_in[9];
  const void* vw0 = d_in[10];
  const void* vb0 = d_in[11];
  const void* qw1 = d_in[12];
  const void* qb1 = d_in[13];
  const void* kw1 = d_in[14];
  const void* kb1 = d_in[15];
  const void* vw1 = d_in[16];
  const void* vb1 = d_in[17];
  const void* lin_w = d_in[18];
  const void* lin_b = d_in[19];
  const void* g0 = d_in[20];
  const void* be0 = d_in[21];
  const void* g1 = d_in[22];
  const void* be1 = d_in[23];

  // Workspace layout (~44.7 MiB total), all offsets 16B-aligned:
  char* w = (char*)d_ws;
  int* idxp = (int*)(w + 0);                  // [0, 2,097,152)
  float* cx = (float*)(w + 2097152);          // 128 KiB
  float* cy = (float*)(w + 2228224);
  float* cz = (float*)(w + 2359296);
  float* tbl = (float*)(w + 2490368);         // 8 KiB
  u16* Bf0 = (u16*)(w + 2498560);             // 96 KiB
  u16* Bf1 = (u16*)(w + 2596864);             // 96 KiB
  u16* BfL = (u16*)(w + 2695168);             // 32 KiB
  u16* featsB = (u16*)(w + 2727936);          // 8 MiB  -> ends 11,116,544
  u16* oB = (u16*)(w + 11116544);             // 8 MiB  (o, then h)  -> ends 19,505,152
  u16* Qb = (u16*)(w + 19505152);             // 8 MiB  -> ends 27,893,760
  u16* KVb = (u16*)(w + 27893760);            // 16 MiB -> ends 44,670,976
  // grid structures alias Qb (dead before gemm L0 writes Qb):
  int* cellStart = (int*)(w + 19505152);      // 4097 ints
  int* cellPtr = (int*)(w + 19537920);        // 4096 ints
  int* pcell = (int*)(w + 19570688);          // 128 KiB
  float4* sortedP = (float4*)(w + 19701760);  // 512 KiB -> ends 20,226,048
  float* h1F = (float*)(w + 19505152);        // 16 MiB (aliases Qb+KVb; dead by then)

  hipLaunchKernelGGL(conv_coords, dim3(128), dim3(256), 0, stream, coords, cx, cy, cz);
  hipLaunchKernelGGL(conv_feats, dim3(16384), dim3(256), 0, stream, coords, feats, featsB);
  hipLaunchKernelGGL(prep_tables, dim3(1), dim3(128), 0, stream, coords,
                     pos_w, pos_b, kw0, kb0, vw0, vb0, pos1_w, pos1_b, kw1, kb1, vw1, vb1, tbl);
  hipLaunchKernelGGL(prep_bfrag, dim3(192), dim3(256), 0, stream, coords, qw0, kw0, vw0, Bf0, 49152);
  hipLaunchKernelGGL(prep_bfrag, dim3(192), dim3(256), 0, stream, coords, qw1, kw1, vw1, Bf1, 49152);
  hipLaunchKernelGGL(prep_bfrag, dim3(64), dim3(256), 0, stream, coords, lin_w, lin_w, lin_w, BfL, 16384);

  // exact grid KNN
  hipLaunchKernelGGL(grid_zero, dim3(17), dim3(256), 0, stream, cellStart);
  hipLaunchKernelGGL(grid_hist, dim3(128), dim3(256), 0, stream, cx, cy, cz, cellStart, pcell);
  hipLaunchKernelGGL(grid_scan, dim3(1), dim3(256), 0, stream, cellStart, cellPtr);
  hipLaunchKernelGGL(grid_scatter, dim3(128), dim3(256), 0, stream, cx, cy, cz, pcell, cellPtr, sortedP);
  hipLaunchKernelGGL(knn_grid, dim3(128), dim3(256), 0, stream, sortedP, cellStart, idxp);

  // layer 0: Q/K/V tables from featsB, attention -> o (bf16) into oB
  hipLaunchKernelGGL(gemm_kernel, dim3(512), dim3(256), 0, stream, coords, featsB, Bf0, qb0, Qb, KVb,
                     (float*)nullptr, 0, 24);
  hipLaunchKernelGGL(attn_kernel, dim3(8192), dim3(256), 0, stream, coords, cx, cy, cz, idxp, Qb, KVb, tbl,
                     (const void*)nullptr, (const void*)nullptr, (const void*)nullptr, oB, 0);
  // layer 1: Q/K/V from o, attention fused with LN0 -> h (bf16) into oB
  hipLaunchKernelGGL(gemm_kernel, dim3(512), dim3(256), 0, stream, coords, oB, Bf1, qb1, Qb, KVb,
                     (float*)nullptr, 0, 24);
  hipLaunchKernelGGL(attn_kernel, dim3(8192), dim3(256), 0, stream, coords, cx, cy, cz, idxp, Qb, KVb, tbl + 1024,
                     feats, g0, be0, oB, 1);
  // h1 = h @ lin_w + lin_b (fp32), out = LN(h + h1) in the input dtype
  hipLaunchKernelGGL(gemm_kernel, dim3(512), dim3(256), 0, stream, coords, oB, BfL, lin_b,
                     (u16*)nullptr, (u16*)nullptr, h1F, 1, 8);
  hipLaunchKernelGGL(ln_final, dim3(8192), dim3(256), 0, stream, coords, oB, h1F, g1, be1, d_out);
}

// Round 5
// 639.058 us; speedup vs baseline: 6.5555x; 1.5060x over previous
//
#include <hip/hip_runtime.h>
#include <stdint.h>

#define NPT 32768

typedef unsigned int u32;
typedef unsigned short u16;
typedef unsigned long long u64;

typedef short v8s __attribute__((ext_vector_type(8)));
typedef float v4f __attribute__((ext_vector_type(4)));

__device__ __forceinline__ float b2f(u16 u) {
  union { u32 u; float f; } x; x.u = ((u32)u) << 16; return x.f;
}
__device__ __forceinline__ u16 f2b(float f) {
  union { float f; u32 u; } x; x.f = f;
  u32 u = x.u;
  return (u16)((u + 0x7fffu + ((u >> 16) & 1u)) >> 16);
}
// dtype probe: coords[0][0] == 0.0 by construction. fp32 -> u16[1] (high half of 0.0f) == 0.
__device__ __forceinline__ bool probe_f32(const void* coords) {
  return ((const u16*)coords)[1] == 0;
}
__device__ __forceinline__ float ldany(const void* p, long i, bool f32) {
  return f32 ? ((const float*)p)[i] : b2f(((const u16*)p)[i]);
}
__device__ __forceinline__ float wsum(float v) {
#pragma unroll
  for (int m = 1; m < 64; m <<= 1) v += __shfl_xor(v, m, 64);
  return v;
}
__device__ __forceinline__ u64 sx64(u64 v, int m) {
  int lo = __shfl_xor((int)(u32)v, m, 64);
  int hi = __shfl_xor((int)(u32)(v >> 32), m, 64);
  return ((u64)(u32)hi << 32) | (u32)lo;
}
__device__ __forceinline__ u64 bc64(u64 v, int src) {
  int lo = __shfl((int)(u32)v, src, 64);
  int hi = __shfl((int)(u32)(v >> 32), src, 64);
  return ((u64)(u32)hi << 32) | (u32)lo;
}

// ---------------- input canonicalization ----------------
__global__ __launch_bounds__(256) void conv_coords(const void* __restrict__ coords,
                                                   float* __restrict__ cx, float* __restrict__ cy,
                                                   float* __restrict__ cz) {
  const bool f32 = probe_f32(coords);
  int i = blockIdx.x * 256 + threadIdx.x;
  cx[i] = ldany(coords, (long)i * 4 + 1, f32);
  cy[i] = ldany(coords, (long)i * 4 + 2, f32);
  cz[i] = ldany(coords, (long)i * 4 + 3, f32);
}

__global__ __launch_bounds__(256) void conv_feats(const void* __restrict__ coords,
                                                  const void* __restrict__ feats, u16* __restrict__ featsB) {
  const bool f32 = probe_f32(coords);
  long i = (long)blockIdx.x * 256 + threadIdx.x;
  featsB[i] = f32 ? f2b(((const float*)feats)[i]) : ((const u16*)feats)[i];
}

// ---------------- exact KNN via 16^3 spatial grid ----------------
#define GC 16
#define GH 6.25f
#define GINV 0.16f

__device__ __forceinline__ int cell1d(float v) {
  int c = (int)(v * GINV);
  return c > (GC - 1) ? (GC - 1) : (c < 0 ? 0 : c);
}

__global__ __launch_bounds__(256) void grid_zero(int* __restrict__ cellStart) {
  int i = blockIdx.x * 256 + threadIdx.x;
  if (i < GC * GC * GC + 1) cellStart[i] = 0;
}

__global__ __launch_bounds__(256) void grid_hist(const float* __restrict__ cx, const float* __restrict__ cy,
                                                 const float* __restrict__ cz, int* __restrict__ cellStart,
                                                 int* __restrict__ pcell) {
  int i = blockIdx.x * 256 + threadIdx.x;
  int c = (cell1d(cz[i]) * GC + cell1d(cy[i])) * GC + cell1d(cx[i]);
  pcell[i] = c;
  atomicAdd(&cellStart[c + 1], 1);
}

__global__ __launch_bounds__(256) void grid_scan(int* __restrict__ cellStart, int* __restrict__ cellPtr) {
  __shared__ int part[256];
  const int t = threadIdx.x;
  int local[16]; int s = 0;
#pragma unroll
  for (int i = 0; i < 16; i++) { local[i] = cellStart[1 + t * 16 + i]; s += local[i]; }
  part[t] = s;
  __syncthreads();
  for (int off = 1; off < 256; off <<= 1) {
    int v = (t >= off) ? part[t - off] : 0;
    __syncthreads();
    part[t] += v;
    __syncthreads();
  }
  int run = (t == 0) ? 0 : part[t - 1];
#pragma unroll
  for (int i = 0; i < 16; i++) {
    int c = t * 16 + i;
    cellPtr[c] = run;
    run += local[i];
    cellStart[c + 1] = run;
  }
}

__global__ __launch_bounds__(256) void grid_scatter(const float* __restrict__ cx, const float* __restrict__ cy,
                                                    const float* __restrict__ cz, const int* __restrict__ pcell,
                                                    int* __restrict__ cellPtr, float4* __restrict__ sortedP) {
  int i = blockIdx.x * 256 + threadIdx.x;
  int c = pcell[i];
  int pos = atomicAdd(&cellPtr[c], 1);
  sortedP[pos] = make_float4(cx[i], cy[i], cz[i], __int_as_float(i));
}

// wave-cooperative: one wave per query; lanes 0..15 end with the sorted top-16 keys.
__global__ __launch_bounds__(256) void knn_grid(const float4* __restrict__ sortedP,
                                                const int* __restrict__ cellStart,
                                                int* __restrict__ idxout) {
  const int lane = threadIdx.x & 63;
  const int q = blockIdx.x * 4 + (threadIdx.x >> 6);
  const float4 p = sortedP[q];
  const float qx = p.x, qy = p.y, qz = p.z;
  const int qi = __float_as_int(p.w);
  const int qcx = cell1d(qx), qcy = cell1d(qy), qcz = cell1d(qz);

  u64 R = ~0ull;  // running sorted top-16 in lanes 0..15 (ascending); +inf elsewhere

  auto key_of = [&](int g) -> u64 {
    float4 sp = sortedP[g];
    float dx = __fsub_rn(qx, sp.x), dy = __fsub_rn(qy, sp.y), dzc = __fsub_rn(qz, sp.z);
    float d = __fadd_rn(__fadd_rn(__fmul_rn(dx, dx), __fmul_rn(dy, dy)), __fmul_rn(dzc, dzc));
    return ((u64)__float_as_uint(d) << 32) | (u32)__float_as_int(sp.w);
  };

  auto batch_merge = [&](u64 key) {
    // bitonic sort of 64 keys across lanes, ascending
#pragma unroll
    for (int k = 2; k <= 64; k <<= 1) {
#pragma unroll
      for (int j = k >> 1; j > 0; j >>= 1) {
        u64 o = sx64(key, j);
        bool up = ((lane & k) == 0);
        bool lower = ((lane & j) == 0);
        u64 mn = key < o ? key : o;
        u64 mx = key < o ? o : key;
        key = (lower == up) ? mn : mx;
      }
    }
    // merge batch top-16 (lanes 0..15, ascending) into R: half-cleaner + 4-stage merge
    u64 s = sx64(key, 15);  // reverse within each 16-group
    u64 mn = R < s ? R : s;
#pragma unroll
    for (int j = 8; j > 0; j >>= 1) {
      u64 o = sx64(mn, j);
      bool lower = ((lane & j) == 0);
      u64 lo = mn < o ? mn : o;
      u64 hi = mn < o ? o : mn;
      mn = lower ? lo : hi;
    }
    R = mn;
  };

  auto scan_range_wave = [&](int s0, int s1) {
    for (int base = s0; base < s1; base += 64) {
      int g = base + lane;
      u64 key = (g < s1) ? key_of(g) : ~0ull;
      batch_merge(key);
    }
  };

  // rings r=0..1 flattened: up to 9 contiguous rows, batched 64-wide at high fill
  {
    int rs[9], rl[9];
#pragma unroll
    for (int dz = -1; dz <= 1; dz++) {
#pragma unroll
      for (int dy = -1; dy <= 1; dy++) {
        int i = (dz + 1) * 3 + (dy + 1);
        int z = qcz + dz, y = qcy + dy;
        if (z < 0 || z > GC - 1 || y < 0 || y > GC - 1) { rs[i] = 0; rl[i] = 0; }
        else {
          int rb = (z * GC + y) * GC;
          int xlo = qcx - 1 < 0 ? 0 : qcx - 1;
          int xhi = qcx + 1 > GC - 1 ? GC - 1 : qcx + 1;
          int s = cellStart[rb + xlo], e = cellStart[rb + xhi + 1];
          rs[i] = s; rl[i] = e - s;
        }
      }
    }
    int cum[10]; cum[0] = 0;
#pragma unroll
    for (int i = 0; i < 9; i++) cum[i + 1] = cum[i] + rl[i];
    int total = cum[9];
    for (int base = 0; base < total; base += 64) {
      int pp = base + lane;
      u64 key = ~0ull;
      if (pp < total) {
        int g = 0;
#pragma unroll
        for (int i = 0; i < 9; i++) {
          if (pp >= cum[i] && pp < cum[i + 1]) g = rs[i] + (pp - cum[i]);
        }
        key = key_of(g);
      }
      batch_merge(key);
    }
  }

  // expansion rings r>=2 (rare): generic, per-row batches
  {
    u64 k15 = bc64(R, 15);
    float d15 = __uint_as_float((u32)(k15 >> 32));
    float b1 = GH * 1.0f;
    if (!(d15 < b1 * b1 * 0.998f)) {
      for (int r = 2; r < GC; ++r) {
        int zlo = qcz - r < 0 ? 0 : qcz - r, zhi = qcz + r > GC - 1 ? GC - 1 : qcz + r;
        for (int z = zlo; z <= zhi; ++z) {
          int adz = z - qcz; adz = adz < 0 ? -adz : adz;
          bool ez = (adz == r);
          int ylo = qcy - r < 0 ? 0 : qcy - r, yhi = qcy + r > GC - 1 ? GC - 1 : qcy + r;
          for (int y = ylo; y <= yhi; ++y) {
            int ady = y - qcy; ady = ady < 0 ? -ady : ady;
            bool ey = (ady == r);
            int rb = (z * GC + y) * GC;
            if (ez || ey) {
              int xlo = qcx - r < 0 ? 0 : qcx - r, xhi = qcx + r > GC - 1 ? GC - 1 : qcx + r;
              scan_range_wave(cellStart[rb + xlo], cellStart[rb + xhi + 1]);
            } else {
              int xm = qcx - r, xp = qcx + r;
              if (xm >= 0) scan_range_wave(cellStart[rb + xm], cellStart[rb + xm + 1]);
              if (xp <= GC - 1) scan_range_wave(cellStart[rb + xp], cellStart[rb + xp + 1]);
            }
          }
        }
        k15 = bc64(R, 15);
        d15 = __uint_as_float((u32)(k15 >> 32));
        float bound = GH * (float)r;
        if (d15 < bound * bound * 0.998f) break;  // margin covers fp rounding
      }
    }
  }

  if (lane < 16) idxout[(size_t)qi * 16 + lane] = (int)(u32)R;
}

// ---------------- small precomputes ----------------
// tbl per layer (1024 floats): [0:384] Wk3(i*128+c), [384:768] Wv3, [768:896] bk_full, [896:1024] bv_full
__global__ __launch_bounds__(128) void prep_tables(
    const void* coords,
    const void* pw0, const void* pb0, const void* kw0, const void* kb0, const void* vw0, const void* vb0,
    const void* pw1, const void* pb1, const void* kw1, const void* kb1, const void* vw1, const void* vb1,
    float* __restrict__ tbl) {
  const bool f32 = probe_f32(coords);
  const int c = threadIdx.x;
  const void* PW[2] = { pw0, pw1 }; const void* PB[2] = { pb0, pb1 };
  const void* KW[2] = { kw0, kw1 }; const void* KB[2] = { kb0, kb1 };
  const void* VW[2] = { vw0, vw1 }; const void* VB[2] = { vb0, vb1 };
#pragma unroll
  for (int l = 0; l < 2; l++) {
    for (int i = 0; i < 3; i++) {
      float ak = 0.f, av = 0.f;
      for (int d = 0; d < 128; d++) {
        float pw = ldany(PW[l], i * 128 + d, f32);
        ak += pw * ldany(KW[l], d * 128 + c, f32);
        av += pw * ldany(VW[l], d * 128 + c, f32);
      }
      tbl[l * 1024 + i * 128 + c] = ak;
      tbl[l * 1024 + 384 + i * 128 + c] = av;
    }
    float bk = 0.f, bv = 0.f;
    for (int d = 0; d < 128; d++) {
      float pb = ldany(PB[l], d, f32);
      bk += pb * ldany(KW[l], d * 128 + c, f32);
      bv += pb * ldany(VW[l], d * 128 + c, f32);
    }
    tbl[l * 1024 + 768 + c] = bk + ldany(KB[l], c, f32);
    tbl[l * 1024 + 896 + c] = bv + ldany(VB[l], c, f32);
  }
}

// repack weights into MFMA B-fragment order: Bf[((tile*4+kq)*64+lane)*8+j] = W[k][col]
__global__ __launch_bounds__(256) void prep_bfrag(const void* __restrict__ coords,
                                                  const void* __restrict__ w0, const void* __restrict__ w1,
                                                  const void* __restrict__ w2, u16* __restrict__ Bf, int nElem) {
  const bool f32 = probe_f32(coords);
  int tid = blockIdx.x * 256 + threadIdx.x;
  if (tid >= nElem) return;
  int j = tid & 7, lane = (tid >> 3) & 63, kq = (tid >> 9) & 3, tile = tid >> 11;
  int k = kq * 32 + ((lane >> 4) << 3) + j;
  int col = tile * 16 + (lane & 15);
  const void* w = (col < 128) ? w0 : ((col < 256) ? w1 : w2);
  long off = (long)k * 128 + (col & 127);
  Bf[tid] = f32 ? f2b(((const float*)w)[off]) : ((const u16*)w)[off];
}

// ---------------- GEMM: A[M,128] bf16 x Bf ----------------
// mode 0: cols 0..127 -> Qb (bf16, +bias); cols 128..383 -> KVb (bf16, no bias)
// mode 1: cols 0..127 -> outF (fp32, +bias)
__global__ __launch_bounds__(256) void gemm_kernel(const void* __restrict__ coords,
                                                   const u16* __restrict__ A, const u16* __restrict__ Bf,
                                                   const void* __restrict__ bias, u16* __restrict__ Qb,
                                                   u16* __restrict__ KVb, float* __restrict__ outF,
                                                   int mode, int ntiles) {
  const bool f32 = probe_f32(coords);
  const int lane = threadIdx.x & 63;
  const int wave = threadIdx.x >> 6;
  const int r0 = blockIdx.x * 64 + wave * 16;
  const int quad = lane >> 4, lr = lane & 15;
  v8s a[4];
#pragma unroll
  for (int kq = 0; kq < 4; kq++) {
    union { uint4 u; v8s s; } c;
    c.u = *(const uint4*)(A + (size_t)(r0 + lr) * 128 + kq * 32 + quad * 8);
    a[kq] = c.s;
  }
  for (int tile = 0; tile < ntiles; ++tile) {
    v4f acc = { 0.f, 0.f, 0.f, 0.f };
#pragma unroll
    for (int kq = 0; kq < 4; kq++) {
      union { uint4 u; v8s s; } c;
      c.u = *(const uint4*)(Bf + ((size_t)(tile * 4 + kq) * 64 + lane) * 8);
      acc = __builtin_amdgcn_mfma_f32_16x16x32_bf16(a[kq], c.s, acc, 0, 0, 0);
    }
    int col = tile * 16 + lr;
    if (mode == 0) {
      if (col < 128) {
        float bb = ldany(bias, col, f32);
#pragma unroll
        for (int r = 0; r < 4; r++) Qb[(size_t)(r0 + quad * 4 + r) * 128 + col] = f2b(acc[r] + bb);
      } else {
#pragma unroll
        for (int r = 0; r < 4; r++) KVb[(size_t)(r0 + quad * 4 + r) * 256 + (col - 128)] = f2b(acc[r]);
      }
    } else {
      float bb = ldany(bias, col, f32);
#pragma unroll
      for (int r = 0; r < 4; r++) outF[(size_t)(r0 + quad * 4 + r) * 128 + col] = acc[r] + bb;
    }
  }
}

// ---------------- fused neighborhood attention (one wave per point) ----------------
// mode 0: out = bf16(o)               (layer-0 output, feeds layer-1 GEMM)
// mode 1: out = bf16(LN(feats+o))     (fused residual+LN with g,be; eps=128)
__global__ __launch_bounds__(256) void attn_kernel(const void* __restrict__ coordsRaw,
                                                   const float* __restrict__ cx, const float* __restrict__ cy,
                                                   const float* __restrict__ cz, const int* __restrict__ idx,
                                                   const u16* __restrict__ Qb, const u16* __restrict__ KVb,
                                                   const float* __restrict__ tbl, const void* __restrict__ feats,
                                                   const void* __restrict__ g, const void* __restrict__ be,
                                                   u16* __restrict__ outB, int mode) {
  const int lane = threadIdx.x & 63;
  const int n = blockIdx.x * 4 + (threadIdx.x >> 6);
  const int c0 = 2 * lane;
  u32 qu = *(const u32*)(Qb + (size_t)n * 128 + c0);
  const float q0 = b2f((u16)(qu & 0xffffu)), q1 = b2f((u16)(qu >> 16));
  float p0 = tbl[c0] * q0 + tbl[c0 + 1] * q1;
  float p1 = tbl[128 + c0] * q0 + tbl[128 + c0 + 1] * q1;
  float p2 = tbl[256 + c0] * q0 + tbl[256 + c0 + 1] * q1;
  float p3 = tbl[768 + c0] * q0 + tbl[768 + c0 + 1] * q1;
  p0 = wsum(p0); p1 = wsum(p1); p2 = wsum(p2); p3 = wsum(p3);
  const float qx = cx[n], qy = cy[n], qz = cz[n];
  int jj[16]; float sc[16], nx[16], ny[16], nz[16];
#pragma unroll
  for (int k = 0; k < 16; k++) {
    int j = idx[(size_t)n * 16 + k];
    jj[k] = j;
    nx[k] = qx - cx[j];
    ny[k] = qy - cy[j];
    nz[k] = qz - cz[j];
    u32 u = *(const u32*)(KVb + (size_t)j * 256 + c0);
    float s = wsum(b2f((u16)(u & 0xffffu)) * q0 + b2f((u16)(u >> 16)) * q1);
    sc[k] = (s + nx[k] * p0 + ny[k] * p1 + nz[k] * p2 + p3) * 0.08838834764831845f; // 1/sqrt(128)
  }
  float m = sc[0];
#pragma unroll
  for (int k = 1; k < 16; k++) m = fmaxf(m, sc[k]);
  float ssum = 0.f;
#pragma unroll
  for (int k = 0; k < 16; k++) { sc[k] = expf(sc[k] - m); ssum += sc[k]; }
  const float inv = 1.0f / ssum;
  float sA = 0.f, wx = 0.f, wy = 0.f, wz = 0.f, a0 = 0.f, a1 = 0.f;
#pragma unroll
  for (int k = 0; k < 16; k++) {
    float a = sc[k] * inv;
    sA += a; wx += a * nx[k]; wy += a * ny[k]; wz += a * nz[k];
    u32 u = *(const u32*)(KVb + (size_t)jj[k] * 256 + 128 + c0);
    a0 += a * b2f((u16)(u & 0xffffu));
    a1 += a * b2f((u16)(u >> 16));
  }
  float o0 = a0 + wx * tbl[384 + c0] + wy * tbl[512 + c0] + wz * tbl[640 + c0] + sA * tbl[896 + c0];
  float o1 = a1 + wx * tbl[384 + c0 + 1] + wy * tbl[512 + c0 + 1] + wz * tbl[640 + c0 + 1] + sA * tbl[896 + c0 + 1];
  if (mode == 1) {
    const bool f32 = probe_f32(coordsRaw);
    float x0 = ldany(feats, (long)n * 128 + c0, f32) + o0;
    float x1 = ldany(feats, (long)n * 128 + c0 + 1, f32) + o1;
    float mu = wsum(x0 + x1) * (1.f / 128.f);
    float d0 = x0 - mu, d1 = x1 - mu;
    float var = wsum(d0 * d0 + d1 * d1) * (1.f / 128.f);
    float rinv = 1.0f / sqrtf(var + 128.0f);
    o0 = d0 * rinv * ldany(g, c0, f32) + ldany(be, c0, f32);
    o1 = d1 * rinv * ldany(g, c0 + 1, f32) + ldany(be, c0 + 1, f32);
  }
  ((u32*)outB)[(size_t)n * 64 + lane] = (u32)f2b(o0) | ((u32)f2b(o1) << 16);
}

// ---------------- final LN: x = bf16(hB) + h1F; out = LN(x)*g+be (eps=128), dual-format store ----------------
__global__ __launch_bounds__(256) void ln_final(const void* __restrict__ coords,
                                                const u16* __restrict__ hB, const float* __restrict__ h1F,
                                                const void* __restrict__ g, const void* __restrict__ be,
                                                void* __restrict__ outAny) {
  const bool f32 = probe_f32(coords);
  const int lane = threadIdx.x & 63;
  const int n = blockIdx.x * 4 + (threadIdx.x >> 6);
  const int c0 = 2 * lane;
  u32 u = *(const u32*)(hB + (size_t)n * 128 + c0);
  float2 h1 = *(const float2*)(h1F + (size_t)n * 128 + c0);
  float x0 = b2f((u16)(u & 0xffffu)) + h1.x;
  float x1 = b2f((u16)(u >> 16)) + h1.y;
  float mu = wsum(x0 + x1) * (1.f / 128.f);
  float d0 = x0 - mu, d1 = x1 - mu;
  float var = wsum(d0 * d0 + d1 * d1) * (1.f / 128.f);
  float rinv = 1.0f / sqrtf(var + 128.0f);
  float y0 = d0 * rinv * ldany(g, c0, f32) + ldany(be, c0, f32);
  float y1 = d1 * rinv * ldany(g, c0 + 1, f32) + ldany(be, c0 + 1, f32);
  if (f32) {
    *(float2*)((float*)outAny + (size_t)n * 128 + c0) = make_float2(y0, y1);
  } else {
    ((u32*)outAny)[(size_t)n * 64 + lane] = (u32)f2b(y0) | ((u32)f2b(y1) << 16);
  }
}

extern "C" void kernel_launch(void* const* d_in, const int* in_sizes, int n_in,
                              void* d_out, int out_size, void* d_ws, size_t ws_size,
                              hipStream_t stream) {
  (void)in_sizes; (void)n_in; (void)out_size; (void)ws_size;
  const void* coords = d_in[0];
  const void* feats = d_in[1];
  const void* pos_w = d_in[2];
  const void* pos_b = d_in[3];
  const void* pos1_w = d_in[4];
  const void* pos1_b = d_in[5];
  const void* qw0 = d_in[6];
  const void* qb0 = d_in[7];
  const void* kw0 = d_in[8];
  const void* kb0 = d_in[9];
  const void* vw0 = d_in[10];
  const void* vb0 = d_in[11];
  const void* qw1 = d_in[12];
  const void* qb1 = d_in[13];
  const void* kw1 = d_in[14];
  const void* kb1 = d_in[15];
  const void* vw1 = d_in[16];
  const void* vb1 = d_in[17];
  const void* lin_w = d_in[18];
  const void* lin_b = d_in[19];
  const void* g0 = d_in[20];
  const void* be0 = d_in[21];
  const void* g1 = d_in[22];
  const void* be1 = d_in[23];

  // Workspace layout (~44.7 MiB total), all offsets 16B-aligned:
  char* w = (char*)d_ws;
  int* idxp = (int*)(w + 0);                  // [0, 2,097,152)
  float* cx = (float*)(w + 2097152);          // 128 KiB
  float* cy = (float*)(w + 2228224);
  float* cz = (float*)(w + 2359296);
  float* tbl = (float*)(w + 2490368);         // 8 KiB
  u16* Bf0 = (u16*)(w + 2498560);             // 96 KiB
  u16* Bf1 = (u16*)(w + 2596864);             // 96 KiB
  u16* BfL = (u16*)(w + 2695168);             // 32 KiB
  u16* featsB = (u16*)(w + 2727936);          // 8 MiB  -> ends 11,116,544
  u16* oB = (u16*)(w + 11116544);             // 8 MiB  (o, then h)  -> ends 19,505,152
  u16* Qb = (u16*)(w + 19505152);             // 8 MiB  -> ends 27,893,760
  u16* KVb = (u16*)(w + 27893760);            // 16 MiB -> ends 44,670,976
  // grid structures alias Qb (dead before gemm L0 writes Qb):
  int* cellStart = (int*)(w + 19505152);      // 4097 ints
  int* cellPtr = (int*)(w + 19537920);        // 4096 ints
  int* pcell = (int*)(w + 19570688);          // 128 KiB
  float4* sortedP = (float4*)(w + 19701760);  // 512 KiB -> ends 20,226,048
  float* h1F = (float*)(w + 19505152);        // 16 MiB (aliases Qb+KVb; dead by then)

  hipLaunchKernelGGL(conv_coords, dim3(128), dim3(256), 0, stream, coords, cx, cy, cz);
  hipLaunchKernelGGL(conv_feats, dim3(16384), dim3(256), 0, stream, coords, feats, featsB);
  hipLaunchKernelGGL(prep_tables, dim3(1), dim3(128), 0, stream, coords,
                     pos_w, pos_b, kw0, kb0, vw0, vb0, pos1_w, pos1_b, kw1, kb1, vw1, vb1, tbl);
  hipLaunchKernelGGL(prep_bfrag, dim3(192), dim3(256), 0, stream, coords, qw0, kw0, vw0, Bf0, 49152);
  hipLaunchKernelGGL(prep_bfrag, dim3(192), dim3(256), 0, stream, coords, qw1, kw1, vw1, Bf1, 49152);
  hipLaunchKernelGGL(prep_bfrag, dim3(64), dim3(256), 0, stream, coords, lin_w, lin_w, lin_w, BfL, 16384);

  // exact grid KNN
  hipLaunchKernelGGL(grid_zero, dim3(17), dim3(256), 0, stream, cellStart);
  hipLaunchKernelGGL(grid_hist, dim3(128), dim3(256), 0, stream, cx, cy, cz, cellStart, pcell);
  hipLaunchKernelGGL(grid_scan, dim3(1), dim3(256), 0, stream, cellStart, cellPtr);
  hipLaunchKernelGGL(grid_scatter, dim3(128), dim3(256), 0, stream, cx, cy, cz, pcell, cellPtr, sortedP);
  hipLaunchKernelGGL(knn_grid, dim3(8192), dim3(256), 0, stream, sortedP, cellStart, idxp);

  // layer 0: Q/K/V tables from featsB, attention -> o (bf16) into oB
  hipLaunchKernelGGL(gemm_kernel, dim3(512), dim3(256), 0, stream, coords, featsB, Bf0, qb0, Qb, KVb,
                     (float*)nullptr, 0, 24);
  hipLaunchKernelGGL(attn_kernel, dim3(8192), dim3(256), 0, stream, coords, cx, cy, cz, idxp, Qb, KVb, tbl,
                     (const void*)nullptr, (const void*)nullptr, (const void*)nullptr, oB, 0);
  // layer 1: Q/K/V from o, attention fused with LN0 -> h (bf16) into oB
  hipLaunchKernelGGL(gemm_kernel, dim3(512), dim3(256), 0, stream, coords, oB, Bf1, qb1, Qb, KVb,
                     (float*)nullptr, 0, 24);
  hipLaunchKernelGGL(attn_kernel, dim3(8192), dim3(256), 0, stream, coords, cx, cy, cz, idxp, Qb, KVb, tbl + 1024,
                     feats, g0, be0, oB, 1);
  // h1 = h @ lin_w + lin_b (fp32), out = LN(h + h1) in the input dtype
  hipLaunchKernelGGL(gemm_kernel, dim3(512), dim3(256), 0, stream, coords, oB, BfL, lin_b,
                     (u16*)nullptr, (u16*)nullptr, h1F, 1, 8);
  hipLaunchKernelGGL(ln_final, dim3(8192), dim3(256), 0, stream, coords, oB, h1F, g1, be1, d_out);
}

// Round 6
// 467.566 us; speedup vs baseline: 8.9599x; 1.3668x over previous
//
#include <hip/hip_runtime.h>
#include <stdint.h>

#define NPT 32768

typedef unsigned int u32;
typedef unsigned short u16;
typedef unsigned long long u64;

typedef short v8s __attribute__((ext_vector_type(8)));
typedef float v4f __attribute__((ext_vector_type(4)));

__device__ __forceinline__ float b2f(u16 u) {
  union { u32 u; float f; } x; x.u = ((u32)u) << 16; return x.f;
}
__device__ __forceinline__ u16 f2b(float f) {
  union { float f; u32 u; } x; x.f = f;
  u32 u = x.u;
  return (u16)((u + 0x7fffu + ((u >> 16) & 1u)) >> 16);
}
// dtype probe: coords[0][0] == 0.0 by construction. fp32 -> u16[1] (high half of 0.0f) == 0.
__device__ __forceinline__ bool probe_f32(const void* coords) {
  return ((const u16*)coords)[1] == 0;
}
__device__ __forceinline__ float ldany(const void* p, long i, bool f32) {
  return f32 ? ((const float*)p)[i] : b2f(((const u16*)p)[i]);
}
__device__ __forceinline__ float wsum(float v) {
#pragma unroll
  for (int m = 1; m < 64; m <<= 1) v += __shfl_xor(v, m, 64);
  return v;
}
__device__ __forceinline__ u64 sx64(u64 v, int m) {
  int lo = __shfl_xor((int)(u32)v, m, 64);
  int hi = __shfl_xor((int)(u32)(v >> 32), m, 64);
  return ((u64)(u32)hi << 32) | (u32)lo;
}
__device__ __forceinline__ u64 bc64(u64 v, int src) {
  int lo = __shfl((int)(u32)v, src, 64);
  int hi = __shfl((int)(u32)(v >> 32), src, 64);
  return ((u64)(u32)hi << 32) | (u32)lo;
}

// ---------------- input canonicalization ----------------
__global__ __launch_bounds__(256) void conv_coords(const void* __restrict__ coords,
                                                   float* __restrict__ cx, float* __restrict__ cy,
                                                   float* __restrict__ cz) {
  const bool f32 = probe_f32(coords);
  int i = blockIdx.x * 256 + threadIdx.x;
  cx[i] = ldany(coords, (long)i * 4 + 1, f32);
  cy[i] = ldany(coords, (long)i * 4 + 2, f32);
  cz[i] = ldany(coords, (long)i * 4 + 3, f32);
}

__global__ __launch_bounds__(256) void conv_feats(const void* __restrict__ coords,
                                                  const void* __restrict__ feats, u16* __restrict__ featsB) {
  const bool f32 = probe_f32(coords);
  long i = (long)blockIdx.x * 256 + threadIdx.x;
  featsB[i] = f32 ? f2b(((const float*)feats)[i]) : ((const u16*)feats)[i];
}

// ---------------- exact KNN via 16^3 spatial grid ----------------
#define GC 16
#define GH 6.25f
#define GINV 0.16f

__device__ __forceinline__ int cell1d(float v) {
  int c = (int)(v * GINV);
  return c > (GC - 1) ? (GC - 1) : (c < 0 ? 0 : c);
}

__global__ __launch_bounds__(256) void grid_zero(int* __restrict__ cellStart) {
  int i = blockIdx.x * 256 + threadIdx.x;
  if (i < GC * GC * GC + 1) cellStart[i] = 0;
}

__global__ __launch_bounds__(256) void grid_hist(const float* __restrict__ cx, const float* __restrict__ cy,
                                                 const float* __restrict__ cz, int* __restrict__ cellStart,
                                                 int* __restrict__ pcell) {
  int i = blockIdx.x * 256 + threadIdx.x;
  int c = (cell1d(cz[i]) * GC + cell1d(cy[i])) * GC + cell1d(cx[i]);
  pcell[i] = c;
  atomicAdd(&cellStart[c + 1], 1);
}

__global__ __launch_bounds__(256) void grid_scan(int* __restrict__ cellStart, int* __restrict__ cellPtr) {
  __shared__ int part[256];
  const int t = threadIdx.x;
  int local[16]; int s = 0;
#pragma unroll
  for (int i = 0; i < 16; i++) { local[i] = cellStart[1 + t * 16 + i]; s += local[i]; }
  part[t] = s;
  __syncthreads();
  for (int off = 1; off < 256; off <<= 1) {
    int v = (t >= off) ? part[t - off] : 0;
    __syncthreads();
    part[t] += v;
    __syncthreads();
  }
  int run = (t == 0) ? 0 : part[t - 1];
#pragma unroll
  for (int i = 0; i < 16; i++) {
    int c = t * 16 + i;
    cellPtr[c] = run;
    run += local[i];
    cellStart[c + 1] = run;
  }
}

__global__ __launch_bounds__(256) void grid_scatter(const float* __restrict__ cx, const float* __restrict__ cy,
                                                    const float* __restrict__ cz, const int* __restrict__ pcell,
                                                    int* __restrict__ cellPtr, float4* __restrict__ sortedP) {
  int i = blockIdx.x * 256 + threadIdx.x;
  int c = pcell[i];
  int pos = atomicAdd(&cellPtr[c], 1);
  sortedP[pos] = make_float4(cx[i], cy[i], cz[i], __int_as_float(i));
}

// wave-cooperative: one wave per query; lanes 0..15 end with the sorted top-16 keys.
__global__ __launch_bounds__(256) void knn_grid(const float4* __restrict__ sortedP,
                                                const int* __restrict__ cellStart,
                                                int* __restrict__ idxout) {
  const int lane = threadIdx.x & 63;
  const int q = blockIdx.x * 4 + (threadIdx.x >> 6);
  const float4 p = sortedP[q];
  const float qx = p.x, qy = p.y, qz = p.z;
  const int qi = __float_as_int(p.w);
  const int qcx = cell1d(qx), qcy = cell1d(qy), qcz = cell1d(qz);

  u64 R = ~0ull;  // running sorted top-16 in lanes 0..15 (ascending); +inf elsewhere

  auto key_of = [&](int g) -> u64 {
    float4 sp = sortedP[g];
    float dx = __fsub_rn(qx, sp.x), dy = __fsub_rn(qy, sp.y), dzc = __fsub_rn(qz, sp.z);
    float d = __fadd_rn(__fadd_rn(__fmul_rn(dx, dx), __fmul_rn(dy, dy)), __fmul_rn(dzc, dzc));
    return ((u64)__float_as_uint(d) << 32) | (u32)__float_as_int(sp.w);
  };

  auto batch_merge = [&](u64 key) {
    // bitonic sort of 64 keys across lanes, ascending
#pragma unroll
    for (int k = 2; k <= 64; k <<= 1) {
#pragma unroll
      for (int j = k >> 1; j > 0; j >>= 1) {
        u64 o = sx64(key, j);
        bool up = ((lane & k) == 0);
        bool lower = ((lane & j) == 0);
        u64 mn = key < o ? key : o;
        u64 mx = key < o ? o : key;
        key = (lower == up) ? mn : mx;
      }
    }
    // merge batch top-16 (lanes 0..15, ascending) into R: half-cleaner + 4-stage merge
    u64 s = sx64(key, 15);  // reverse within each 16-group
    u64 mn = R < s ? R : s;
#pragma unroll
    for (int j = 8; j > 0; j >>= 1) {
      u64 o = sx64(mn, j);
      bool lower = ((lane & j) == 0);
      u64 lo = mn < o ? mn : o;
      u64 hi = mn < o ? o : mn;
      mn = lower ? lo : hi;
    }
    R = mn;
  };

  auto scan_range_wave = [&](int s0, int s1) {
    for (int base = s0; base < s1; base += 64) {
      int g = base + lane;
      u64 key = (g < s1) ? key_of(g) : ~0ull;
      batch_merge(key);
    }
  };

  // rings r=0..1 flattened: up to 9 contiguous rows, batched 64-wide at high fill
  {
    int rs[9], rl[9];
#pragma unroll
    for (int dz = -1; dz <= 1; dz++) {
#pragma unroll
      for (int dy = -1; dy <= 1; dy++) {
        int i = (dz + 1) * 3 + (dy + 1);
        int z = qcz + dz, y = qcy + dy;
        if (z < 0 || z > GC - 1 || y < 0 || y > GC - 1) { rs[i] = 0; rl[i] = 0; }
        else {
          int rb = (z * GC + y) * GC;
          int xlo = qcx - 1 < 0 ? 0 : qcx - 1;
          int xhi = qcx + 1 > GC - 1 ? GC - 1 : qcx + 1;
          int s = cellStart[rb + xlo], e = cellStart[rb + xhi + 1];
          rs[i] = s; rl[i] = e - s;
        }
      }
    }
    int cum[10]; cum[0] = 0;
#pragma unroll
    for (int i = 0; i < 9; i++) cum[i + 1] = cum[i] + rl[i];
    int total = cum[9];
    for (int base = 0; base < total; base += 64) {
      int pp = base + lane;
      u64 key = ~0ull;
      if (pp < total) {
        int g = 0;
#pragma unroll
        for (int i = 0; i < 9; i++) {
          if (pp >= cum[i] && pp < cum[i + 1]) g = rs[i] + (pp - cum[i]);
        }
        key = key_of(g);
      }
      batch_merge(key);
    }
  }

  // expansion rings r>=2 (rare): generic, per-row batches
  {
    u64 k15 = bc64(R, 15);
    float d15 = __uint_as_float((u32)(k15 >> 32));
    float b1 = GH * 1.0f;
    if (!(d15 < b1 * b1 * 0.998f)) {
      for (int r = 2; r < GC; ++r) {
        int zlo = qcz - r < 0 ? 0 : qcz - r, zhi = qcz + r > GC - 1 ? GC - 1 : qcz + r;
        for (int z = zlo; z <= zhi; ++z) {
          int adz = z - qcz; adz = adz < 0 ? -adz : adz;
          bool ez = (adz == r);
          int ylo = qcy - r < 0 ? 0 : qcy - r, yhi = qcy + r > GC - 1 ? GC - 1 : qcy + r;
          for (int y = ylo; y <= yhi; ++y) {
            int ady = y - qcy; ady = ady < 0 ? -ady : ady;
            bool ey = (ady == r);
            int rb = (z * GC + y) * GC;
            if (ez || ey) {
              int xlo = qcx - r < 0 ? 0 : qcx - r, xhi = qcx + r > GC - 1 ? GC - 1 : qcx + r;
              scan_range_wave(cellStart[rb + xlo], cellStart[rb + xhi + 1]);
            } else {
              int xm = qcx - r, xp = qcx + r;
              if (xm >= 0) scan_range_wave(cellStart[rb + xm], cellStart[rb + xm + 1]);
              if (xp <= GC - 1) scan_range_wave(cellStart[rb + xp], cellStart[rb + xp + 1]);
            }
          }
        }
        k15 = bc64(R, 15);
        d15 = __uint_as_float((u32)(k15 >> 32));
        float bound = GH * (float)r;
        if (d15 < bound * bound * 0.998f) break;  // margin covers fp rounding
      }
    }
  }

  if (lane < 16) idxout[(size_t)qi * 16 + lane] = (int)(u32)R;
}

// ---------------- small precomputes ----------------
// tbl per layer (1024 floats): [0:384] Wk3(i*128+c), [384:768] Wv3, [768:896] bk_full, [896:1024] bv_full
// one wave per output element; 2048 outputs total (2 layers x 1024)
__global__ __launch_bounds__(256) void prep_tables(
    const void* coords,
    const void* pw0, const void* pb0, const void* kw0, const void* kb0, const void* vw0, const void* vb0,
    const void* pw1, const void* pb1, const void* kw1, const void* kb1, const void* vw1, const void* vb1,
    float* __restrict__ tbl) {
  const bool f32 = probe_f32(coords);
  const int lane = threadIdx.x & 63;
  const int o = blockIdx.x * 4 + (threadIdx.x >> 6);  // 0..2047
  const int l = o >> 10;
  const int rem = o & 1023;
  const void* PW = l ? pw1 : pw0;
  const void* PB = l ? pb1 : pb0;
  const void* KW = l ? kw1 : kw0;
  const void* KB = l ? kb1 : kb0;
  const void* VW = l ? vw1 : vw0;
  const void* VB = l ? vb1 : vb0;
  float acc, extra = 0.f;
  if (rem < 768) {
    bool isV = rem >= 384;
    int r2 = isV ? rem - 384 : rem;
    int i = r2 >> 7, c = r2 & 127;
    const void* W = isV ? VW : KW;
    acc = ldany(PW, i * 128 + lane, f32) * ldany(W, (long)lane * 128 + c, f32)
        + ldany(PW, i * 128 + lane + 64, f32) * ldany(W, (long)(lane + 64) * 128 + c, f32);
  } else {
    bool isV = rem >= 896;
    int c = rem & 127;
    const void* W = isV ? VW : KW;
    const void* B = isV ? VB : KB;
    acc = ldany(PB, lane, f32) * ldany(W, (long)lane * 128 + c, f32)
        + ldany(PB, lane + 64, f32) * ldany(W, (long)(lane + 64) * 128 + c, f32);
    extra = ldany(B, c, f32);
  }
  acc = wsum(acc) + extra;
  if (lane == 0) tbl[l * 1024 + rem] = acc;
}

// repack weights into MFMA B-fragment order: Bf[((tile*4+kq)*64+lane)*8+j] = W[k][col]
__global__ __launch_bounds__(256) void prep_bfrag(const void* __restrict__ coords,
                                                  const void* __restrict__ w0, const void* __restrict__ w1,
                                                  const void* __restrict__ w2, u16* __restrict__ Bf, int nElem) {
  const bool f32 = probe_f32(coords);
  int tid = blockIdx.x * 256 + threadIdx.x;
  if (tid >= nElem) return;
  int j = tid & 7, lane = (tid >> 3) & 63, kq = (tid >> 9) & 3, tile = tid >> 11;
  int k = kq * 32 + ((lane >> 4) << 3) + j;
  int col = tile * 16 + (lane & 15);
  const void* w = (col < 128) ? w0 : ((col < 256) ? w1 : w2);
  long off = (long)k * 128 + (col & 127);
  Bf[tid] = f32 ? f2b(((const float*)w)[off]) : ((const u16*)w)[off];
}

// ---------------- GEMM: A[M,128] bf16 x Bf ----------------
// mode 0: cols 0..127 -> Qb (bf16, +bias); cols 128..383 -> KVb (bf16, no bias)
// mode 1: cols 0..127 -> outF (fp32, +bias)
__global__ __launch_bounds__(256) void gemm_kernel(const void* __restrict__ coords,
                                                   const u16* __restrict__ A, const u16* __restrict__ Bf,
                                                   const void* __restrict__ bias, u16* __restrict__ Qb,
                                                   u16* __restrict__ KVb, float* __restrict__ outF,
                                                   int mode, int ntiles) {
  const bool f32 = probe_f32(coords);
  const int lane = threadIdx.x & 63;
  const int wave = threadIdx.x >> 6;
  const int r0 = blockIdx.x * 64 + wave * 16;
  const int quad = lane >> 4, lr = lane & 15;
  v8s a[4];
#pragma unroll
  for (int kq = 0; kq < 4; kq++) {
    union { uint4 u; v8s s; } c;
    c.u = *(const uint4*)(A + (size_t)(r0 + lr) * 128 + kq * 32 + quad * 8);
    a[kq] = c.s;
  }
  for (int tile = 0; tile < ntiles; ++tile) {
    v4f acc = { 0.f, 0.f, 0.f, 0.f };
#pragma unroll
    for (int kq = 0; kq < 4; kq++) {
      union { uint4 u; v8s s; } c;
      c.u = *(const uint4*)(Bf + ((size_t)(tile * 4 + kq) * 64 + lane) * 8);
      acc = __builtin_amdgcn_mfma_f32_16x16x32_bf16(a[kq], c.s, acc, 0, 0, 0);
    }
    int col = tile * 16 + lr;
    if (mode == 0) {
      if (col < 128) {
        float bb = ldany(bias, col, f32);
#pragma unroll
        for (int r = 0; r < 4; r++) Qb[(size_t)(r0 + quad * 4 + r) * 128 + col] = f2b(acc[r] + bb);
      } else {
#pragma unroll
        for (int r = 0; r < 4; r++) KVb[(size_t)(r0 + quad * 4 + r) * 256 + (col - 128)] = f2b(acc[r]);
      }
    } else {
      float bb = ldany(bias, col, f32);
#pragma unroll
      for (int r = 0; r < 4; r++) outF[(size_t)(r0 + quad * 4 + r) * 128 + col] = acc[r] + bb;
    }
  }
}

// ---------------- fused neighborhood attention (one wave per point) ----------------
// mode 0: out = bf16(o)               (layer-0 output, feeds layer-1 GEMM)
// mode 1: out = bf16(LN(feats+o))     (fused residual+LN with g,be; eps=128)
__global__ __launch_bounds__(256) void attn_kernel(const void* __restrict__ coordsRaw,
                                                   const float* __restrict__ cx, const float* __restrict__ cy,
                                                   const float* __restrict__ cz, const int* __restrict__ idx,
                                                   const u16* __restrict__ Qb, const u16* __restrict__ KVb,
                                                   const float* __restrict__ tbl, const void* __restrict__ feats,
                                                   const void* __restrict__ g, const void* __restrict__ be,
                                                   u16* __restrict__ outB, int mode) {
  const int lane = threadIdx.x & 63;
  const int n = blockIdx.x * 4 + (threadIdx.x >> 6);
  const int c0 = 2 * lane;
  u32 qu = *(const u32*)(Qb + (size_t)n * 128 + c0);
  const float q0 = b2f((u16)(qu & 0xffffu)), q1 = b2f((u16)(qu >> 16));
  float p0 = tbl[c0] * q0 + tbl[c0 + 1] * q1;
  float p1 = tbl[128 + c0] * q0 + tbl[128 + c0 + 1] * q1;
  float p2 = tbl[256 + c0] * q0 + tbl[256 + c0 + 1] * q1;
  float p3 = tbl[768 + c0] * q0 + tbl[768 + c0 + 1] * q1;
  p0 = wsum(p0); p1 = wsum(p1); p2 = wsum(p2); p3 = wsum(p3);
  const float qx = cx[n], qy = cy[n], qz = cz[n];
  int jj[16]; float sc[16], nx[16], ny[16], nz[16];
#pragma unroll
  for (int k = 0; k < 16; k++) {
    int j = idx[(size_t)n * 16 + k];
    jj[k] = j;
    nx[k] = qx - cx[j];
    ny[k] = qy - cy[j];
    nz[k] = qz - cz[j];
    u32 u = *(const u32*)(KVb + (size_t)j * 256 + c0);
    float s = wsum(b2f((u16)(u & 0xffffu)) * q0 + b2f((u16)(u >> 16)) * q1);
    sc[k] = (s + nx[k] * p0 + ny[k] * p1 + nz[k] * p2 + p3) * 0.08838834764831845f; // 1/sqrt(128)
  }
  float m = sc[0];
#pragma unroll
  for (int k = 1; k < 16; k++) m = fmaxf(m, sc[k]);
  float ssum = 0.f;
#pragma unroll
  for (int k = 0; k < 16; k++) { sc[k] = expf(sc[k] - m); ssum += sc[k]; }
  const float inv = 1.0f / ssum;
  float sA = 0.f, wx = 0.f, wy = 0.f, wz = 0.f, a0 = 0.f, a1 = 0.f;
#pragma unroll
  for (int k = 0; k < 16; k++) {
    float a = sc[k] * inv;
    sA += a; wx += a * nx[k]; wy += a * ny[k]; wz += a * nz[k];
    u32 u = *(const u32*)(KVb + (size_t)jj[k] * 256 + 128 + c0);
    a0 += a * b2f((u16)(u & 0xffffu));
    a1 += a * b2f((u16)(u >> 16));
  }
  float o0 = a0 + wx * tbl[384 + c0] + wy * tbl[512 + c0] + wz * tbl[640 + c0] + sA * tbl[896 + c0];
  float o1 = a1 + wx * tbl[384 + c0 + 1] + wy * tbl[512 + c0 + 1] + wz * tbl[640 + c0 + 1] + sA * tbl[896 + c0 + 1];
  if (mode == 1) {
    const bool f32 = probe_f32(coordsRaw);
    float x0 = ldany(feats, (long)n * 128 + c0, f32) + o0;
    float x1 = ldany(feats, (long)n * 128 + c0 + 1, f32) + o1;
    float mu = wsum(x0 + x1) * (1.f / 128.f);
    float d0 = x0 - mu, d1 = x1 - mu;
    float var = wsum(d0 * d0 + d1 * d1) * (1.f / 128.f);
    float rinv = 1.0f / sqrtf(var + 128.0f);
    o0 = d0 * rinv * ldany(g, c0, f32) + ldany(be, c0, f32);
    o1 = d1 * rinv * ldany(g, c0 + 1, f32) + ldany(be, c0 + 1, f32);
  }
  ((u32*)outB)[(size_t)n * 64 + lane] = (u32)f2b(o0) | ((u32)f2b(o1) << 16);
}

// ---------------- final LN: x = bf16(hB) + h1F; out = LN(x)*g+be (eps=128), dual-format store ----------------
__global__ __launch_bounds__(256) void ln_final(const void* __restrict__ coords,
                                                const u16* __restrict__ hB, const float* __restrict__ h1F,
                                                const void* __restrict__ g, const void* __restrict__ be,
                                                void* __restrict__ outAny) {
  const bool f32 = probe_f32(coords);
  const int lane = threadIdx.x & 63;
  const int n = blockIdx.x * 4 + (threadIdx.x >> 6);
  const int c0 = 2 * lane;
  u32 u = *(const u32*)(hB + (size_t)n * 128 + c0);
  float2 h1 = *(const float2*)(h1F + (size_t)n * 128 + c0);
  float x0 = b2f((u16)(u & 0xffffu)) + h1.x;
  float x1 = b2f((u16)(u >> 16)) + h1.y;
  float mu = wsum(x0 + x1) * (1.f / 128.f);
  float d0 = x0 - mu, d1 = x1 - mu;
  float var = wsum(d0 * d0 + d1 * d1) * (1.f / 128.f);
  float rinv = 1.0f / sqrtf(var + 128.0f);
  float y0 = d0 * rinv * ldany(g, c0, f32) + ldany(be, c0, f32);
  float y1 = d1 * rinv * ldany(g, c0 + 1, f32) + ldany(be, c0 + 1, f32);
  if (f32) {
    *(float2*)((float*)outAny + (size_t)n * 128 + c0) = make_float2(y0, y1);
  } else {
    ((u32*)outAny)[(size_t)n * 64 + lane] = (u32)f2b(y0) | ((u32)f2b(y1) << 16);
  }
}

extern "C" void kernel_launch(void* const* d_in, const int* in_sizes, int n_in,
                              void* d_out, int out_size, void* d_ws, size_t ws_size,
                              hipStream_t stream) {
  (void)in_sizes; (void)n_in; (void)out_size; (void)ws_size;
  const void* coords = d_in[0];
  const void* feats = d_in[1];
  const void* pos_w = d_in[2];
  const void* pos_b = d_in[3];
  const void* pos1_w = d_in[4];
  const void* pos1_b = d_in[5];
  const void* qw0 = d_in[6];
  const void* qb0 = d_in[7];
  const void* kw0 = d_in[8];
  const void* kb0 = d_in[9];
  const void* vw0 = d_in[10];
  const void* vb0 = d_in[11];
  const void* qw1 = d_in[12];
  const void* qb1 = d_in[13];
  const void* kw1 = d_in[14];
  const void* kb1 = d_in[15];
  const void* vw1 = d_in[16];
  const void* vb1 = d_in[17];
  const void* lin_w = d_in[18];
  const void* lin_b = d_in[19];
  const void* g0 = d_in[20];
  const void* be0 = d_in[21];
  const void* g1 = d_in[22];
  const void* be1 = d_in[23];

  // Workspace layout (~44.7 MiB total), all offsets 16B-aligned:
  char* w = (char*)d_ws;
  int* idxp = (int*)(w + 0);                  // [0, 2,097,152)
  float* cx = (float*)(w + 2097152);          // 128 KiB
  float* cy = (float*)(w + 2228224);
  float* cz = (float*)(w + 2359296);
  float* tbl = (float*)(w + 2490368);         // 8 KiB
  u16* Bf0 = (u16*)(w + 2498560);             // 96 KiB
  u16* Bf1 = (u16*)(w + 2596864);             // 96 KiB
  u16* BfL = (u16*)(w + 2695168);             // 32 KiB
  u16* featsB = (u16*)(w + 2727936);          // 8 MiB  -> ends 11,116,544
  u16* oB = (u16*)(w + 11116544);             // 8 MiB  (o, then h)  -> ends 19,505,152
  u16* Qb = (u16*)(w + 19505152);             // 8 MiB  -> ends 27,893,760
  u16* KVb = (u16*)(w + 27893760);            // 16 MiB -> ends 44,670,976
  // grid structures alias Qb (dead before gemm L0 writes Qb):
  int* cellStart = (int*)(w + 19505152);      // 4097 ints
  int* cellPtr = (int*)(w + 19537920);        // 4096 ints
  int* pcell = (int*)(w + 19570688);          // 128 KiB
  float4* sortedP = (float4*)(w + 19701760);  // 512 KiB -> ends 20,226,048
  float* h1F = (float*)(w + 19505152);        // 16 MiB (aliases Qb+KVb; dead by then)

  hipLaunchKernelGGL(conv_coords, dim3(128), dim3(256), 0, stream, coords, cx, cy, cz);
  hipLaunchKernelGGL(conv_feats, dim3(16384), dim3(256), 0, stream, coords, feats, featsB);
  hipLaunchKernelGGL(prep_tables, dim3(512), dim3(256), 0, stream, coords,
                     pos_w, pos_b, kw0, kb0, vw0, vb0, pos1_w, pos1_b, kw1, kb1, vw1, vb1, tbl);
  hipLaunchKernelGGL(prep_bfrag, dim3(192), dim3(256), 0, stream, coords, qw0, kw0, vw0, Bf0, 49152);
  hipLaunchKernelGGL(prep_bfrag, dim3(192), dim3(256), 0, stream, coords, qw1, kw1, vw1, Bf1, 49152);
  hipLaunchKernelGGL(prep_bfrag, dim3(64), dim3(256), 0, stream, coords, lin_w, lin_w, lin_w, BfL, 16384);

  // exact grid KNN
  hipLaunchKernelGGL(grid_zero, dim3(17), dim3(256), 0, stream, cellStart);
  hipLaunchKernelGGL(grid_hist, dim3(128), dim3(256), 0, stream, cx, cy, cz, cellStart, pcell);
  hipLaunchKernelGGL(grid_scan, dim3(1), dim3(256), 0, stream, cellStart, cellPtr);
  hipLaunchKernelGGL(grid_scatter, dim3(128), dim3(256), 0, stream, cx, cy, cz, pcell, cellPtr, sortedP);
  hipLaunchKernelGGL(knn_grid, dim3(8192), dim3(256), 0, stream, sortedP, cellStart, idxp);

  // layer 0: Q/K/V tables from featsB, attention -> o (bf16) into oB
  hipLaunchKernelGGL(gemm_kernel, dim3(512), dim3(256), 0, stream, coords, featsB, Bf0, qb0, Qb, KVb,
                     (float*)nullptr, 0, 24);
  hipLaunchKernelGGL(attn_kernel, dim3(8192), dim3(256), 0, stream, coords, cx, cy, cz, idxp, Qb, KVb, tbl,
                     (const void*)nullptr, (const void*)nullptr, (const void*)nullptr, oB, 0);
  // layer 1: Q/K/V from o, attention fused with LN0 -> h (bf16) into oB
  hipLaunchKernelGGL(gemm_kernel, dim3(512), dim3(256), 0, stream, coords, oB, Bf1, qb1, Qb, KVb,
                     (float*)nullptr, 0, 24);
  hipLaunchKernelGGL(attn_kernel, dim3(8192), dim3(256), 0, stream, coords, cx, cy, cz, idxp, Qb, KVb, tbl + 1024,
                     feats, g0, be0, oB, 1);
  // h1 = h @ lin_w + lin_b (fp32), out = LN(h + h1) in the input dtype
  hipLaunchKernelGGL(gemm_kernel, dim3(512), dim3(256), 0, stream, coords, oB, BfL, lin_b,
                     (u16*)nullptr, (u16*)nullptr, h1F, 1, 8);
  hipLaunchKernelGGL(ln_final, dim3(8192), dim3(256), 0, stream, coords, oB, h1F, g1, be1, d_out);
}